// Round 4
// baseline (389.853 us; speedup 1.0000x reference)
//
#include <hip/hip_runtime.h>
#include <stdint.h>

typedef unsigned short u16;
typedef unsigned int u32;
typedef __attribute__((ext_vector_type(8))) short bf16x8;
typedef __attribute__((ext_vector_type(4))) float f32x4;

__device__ __forceinline__ u16 f2b(float f) {
    union { float f; u32 u; } t; t.f = f;
    return (u16)((t.u + 0x7FFFu + ((t.u >> 16) & 1u)) >> 16);
}
__device__ __forceinline__ float b2f(u16 h) {
    union { u32 u; float f; } t; t.u = ((u32)h) << 16;
    return t.f;
}
__device__ __forceinline__ u32 pack2(float a, float b) {
    return (u32)f2b(a) | ((u32)f2b(b) << 16);
}

// ---------------- fused fp32 -> bf16 cast (x + 4 weights, one launch) ----------------
__global__ void cast_all_kernel(const float* __restrict__ x,
                                const float* __restrict__ Wq, const float* __restrict__ Wk,
                                const float* __restrict__ Wv, const float* __restrict__ Wo,
                                u16* __restrict__ xb, u16* __restrict__ Wqb, u16* __restrict__ Wkb,
                                u16* __restrict__ Wvb, u16* __restrict__ Wob) {
    int i = blockIdx.x * blockDim.x + threadIdx.x;  // float4 index, total 2097152
    const float* s; u16* d; int off;
    if (i < 1048576) { s = x; d = xb; off = i; }
    else {
        int j = i - 1048576;
        int w = j >> 18; off = j & 262143;
        if (w == 0) { s = Wq; d = Wqb; }
        else if (w == 1) { s = Wk; d = Wkb; }
        else if (w == 2) { s = Wv; d = Wvb; }
        else { s = Wo; d = Wob; }
    }
    float4 f = ((const float4*)s)[off];
    ((uint2*)d)[off] = make_uint2(pack2(f.x, f.y), pack2(f.z, f.w));
}

// ---------------- GEMM: y = A @ W^T + bias ----------------
#define GT 128
#define GK 32
#define GLD 40

template<int MODE>
__device__ __forceinline__ void gemm_core(
    const u16* __restrict__ A, const u16* __restrict__ W, const float* __restrict__ bias,
    u16* __restrict__ obf, u16* __restrict__ vtout, float* __restrict__ ofp)
{
    __shared__ u16 As[GT * GLD];
    __shared__ u16 Bs[GT * GLD];
    const int tid = threadIdx.x;
    const int lane = tid & 63, w = tid >> 6;
    const int wm = w >> 1, wn = w & 1;
    const int l15 = lane & 15, quad = lane >> 4;
    const int M0 = blockIdx.y * GT, N0 = blockIdx.x * GT;

    f32x4 acc[4][4];
#pragma unroll
    for (int i = 0; i < 4; i++)
#pragma unroll
        for (int j = 0; j < 4; j++) acc[i][j] = (f32x4){0.f, 0.f, 0.f, 0.f};

    const int srow = tid >> 1, shalf = tid & 1;
    const u16* Ag = A + (size_t)(M0 + srow) * 1024 + shalf * 16;
    const u16* Wg = W + (size_t)(N0 + srow) * 1024 + shalf * 16;
    u16* Asw = As + srow * GLD + shalf * 16;
    u16* Bsw = Bs + srow * GLD + shalf * 16;

    for (int k0 = 0; k0 < 1024; k0 += GK) {
        uint4 a0 = *(const uint4*)(Ag + k0);
        uint4 a1 = *(const uint4*)(Ag + k0 + 8);
        uint4 b0 = *(const uint4*)(Wg + k0);
        uint4 b1 = *(const uint4*)(Wg + k0 + 8);
        __syncthreads();
        *(uint4*)(Asw) = a0;
        *(uint4*)(Asw + 8) = a1;
        *(uint4*)(Bsw) = b0;
        *(uint4*)(Bsw + 8) = b1;
        __syncthreads();
        bf16x8 af[4], bf[4];
#pragma unroll
        for (int mi = 0; mi < 4; mi++)
            af[mi] = *(const bf16x8*)(As + (wm * 64 + mi * 16 + l15) * GLD + quad * 8);
#pragma unroll
        for (int ni = 0; ni < 4; ni++)
            bf[ni] = *(const bf16x8*)(Bs + (wn * 64 + ni * 16 + l15) * GLD + quad * 8);
#pragma unroll
        for (int mi = 0; mi < 4; mi++)
#pragma unroll
            for (int ni = 0; ni < 4; ni++)
                acc[mi][ni] = __builtin_amdgcn_mfma_f32_16x16x32_bf16(af[mi], bf[ni], acc[mi][ni], 0, 0, 0);
    }

#pragma unroll
    for (int mi = 0; mi < 4; mi++)
#pragma unroll
        for (int ni = 0; ni < 4; ni++) {
            int n = N0 + wn * 64 + ni * 16 + l15;
            float bias_n = bias[n];
            float vals[4];
#pragma unroll
            for (int r = 0; r < 4; r++)
                vals[r] = acc[mi][ni][r] + bias_n;
            int m0 = M0 + wm * 64 + mi * 16 + quad * 4;
            if (MODE == 0) {
                int b = m0 >> 11, t = m0 & 2047;
                int h = n >> 6, hd = n & 63;
#pragma unroll
                for (int r = 0; r < 4; r++)
                    obf[((size_t)((b * 16 + h) * 2048 + (t + r)) << 6) + hd] = f2b(vals[r]);
                if (vtout) {  // also emit V^T: [bh*64+hd][t], t fast => packed b64
                    *(uint2*)(vtout + ((size_t)((b * 16 + h) * 64 + hd)) * 2048 + t) =
                        make_uint2(pack2(vals[0], vals[1]), pack2(vals[2], vals[3]));
                }
            } else {
#pragma unroll
                for (int r = 0; r < 4; r++)
                    ofp[(size_t)(m0 + r) * 1024 + n] = vals[r];
            }
        }
}

__global__ __launch_bounds__(256) void gemm_qkv_kernel(
    const u16* __restrict__ xb,
    const u16* __restrict__ Wq, const u16* __restrict__ Wk, const u16* __restrict__ Wv,
    const float* __restrict__ bq, const float* __restrict__ bk, const float* __restrict__ bv,
    u16* __restrict__ q, u16* __restrict__ k, u16* __restrict__ v, u16* __restrict__ vT)
{
    const u16* W; const float* bias; u16* o; u16* vt = nullptr;
    if (blockIdx.z == 0)      { W = Wq; bias = bq; o = q; }
    else if (blockIdx.z == 1) { W = Wk; bias = bk; o = k; }
    else                      { W = Wv; bias = bv; o = v; vt = vT; }
    gemm_core<0>(xb, W, bias, o, vt, nullptr);
}

__global__ __launch_bounds__(256) void gemm_out_kernel(
    const u16* __restrict__ ao, const u16* __restrict__ Wo, const float* __restrict__ bo,
    float* __restrict__ out)
{
    gemm_core<1>(ao, Wo, bo, nullptr, nullptr, out);
}

// ---------------- build extended q/k rows (96 dims), temp*log2e folded into qe ----------------
__global__ void build_ext_kernel(
    const u16* __restrict__ q, const u16* __restrict__ k, const u16* __restrict__ v,
    const float* __restrict__ Wqs, const float* __restrict__ bqs,
    const float* __restrict__ Wks, const float* __restrict__ bks,
    const float* __restrict__ Wvs, const float* __restrict__ bvs,
    const float* __restrict__ temp_p,
    u16* __restrict__ qe, u16* __restrict__ ke)
{
    int row = blockIdx.x * blockDim.x + threadIdx.x;
    if (row >= 2 * 16 * 2048) return;
    const float temp = *temp_p * 1.44269504088896f;  // scores emerge in log2 domain
    const u16* qr = q + (size_t)row * 64;
    const u16* kr = k + (size_t)row * 64;
    const u16* vr = v + (size_t)row * 64;

    float qs0 = bqs[0], qs1 = bqs[1], qs2 = bqs[2];
    float ks0 = bks[0], ks1 = bks[1], ks2 = bks[2];
    float vs0 = bvs[0], vs1 = bvs[1], vs2 = bvs[2];
#pragma unroll
    for (int j = 0; j < 64; j += 8) {
        bf16x8 qv = *(const bf16x8*)(qr + j);
        bf16x8 kv = *(const bf16x8*)(kr + j);
        bf16x8 vv = *(const bf16x8*)(vr + j);
#pragma unroll
        for (int i = 0; i < 8; i++) {
            float qf = b2f((u16)qv[i]);
            float kf = b2f((u16)kv[i]);
            float vf = b2f((u16)vv[i]);
            qs0 += qf * Wqs[j + i]; qs1 += qf * Wqs[64 + j + i]; qs2 += qf * Wqs[128 + j + i];
            ks0 += kf * Wks[j + i]; ks1 += kf * Wks[64 + j + i]; ks2 += kf * Wks[128 + j + i];
            vs0 += vf * Wvs[j + i]; vs1 += vf * Wvs[64 + j + i]; vs2 += vf * Wvs[128 + j + i];
        }
    }
    float c0 = ks1 * vs2 - ks2 * vs1;
    float c1 = ks2 * vs0 - ks0 * vs2;
    float c2 = ks0 * vs1 - ks1 * vs0;

    u16* qer = qe + (size_t)row * 96;
    u16* ker = ke + (size_t)row * 96;
#pragma unroll
    for (int j = 0; j < 64; j += 8) {
        bf16x8 qv = *(const bf16x8*)(qr + j);
        bf16x8 sq;
#pragma unroll
        for (int i = 0; i < 8; i++) sq[i] = (short)f2b(b2f((u16)qv[i]) * temp);
        *(bf16x8*)(qer + j) = sq;
        *(bf16x8*)(ker + j) = *(const bf16x8*)(kr + j);
    }
    *(uint2*)(qer + 64) = make_uint2(pack2(qs0 * temp, qs1 * temp), (u32)f2b(qs2 * temp));
    *(uint2*)(ker + 64) = make_uint2(pack2(c0, c1), (u32)f2b(c2));
    uint2 z = make_uint2(0u, 0u);
#pragma unroll
    for (int j = 68; j < 96; j += 4) {
        *(uint2*)(qer + j) = z;
        *(uint2*)(ker + j) = z;
    }
}

// ---------------- flash attention: transposed S, max-free softmax (bounded scores),
// 2 waves x 4 q-subtiles, XOR-swizzled b128 LDS ----------------
// Ks: [key 0..63][16B chunks, stride 16, 12 used]  16 KB
// Vt: [d 0..63][8 chunks]                           8 KB
// Ps: [q 0..127][8 chunks]                         16 KB (wave-private rows, no barrier)
__global__ __launch_bounds__(128) void attn_kernel(
    const u16* __restrict__ qe, const u16* __restrict__ ke, const u16* __restrict__ vT,
    u16* __restrict__ out)
{
    __shared__ u16 Ks[64 * 128];
    __shared__ u16 Vt[64 * 64];
    __shared__ u16 Ps[128 * 64];

    const int tid = threadIdx.x;
    const int lane = tid & 63, w = tid >> 6;  // w in {0,1}
    const int l15 = lane & 15, quad = lane >> 4;
    const int lsw = l15 & 7;
    const int bh = blockIdx.y;
    const int q0 = blockIdx.x * 128;

    const u16* qeb = qe + (size_t)bh * 2048 * 96;
    const u16* keb = ke + (size_t)bh * 2048 * 96;
    const u16* vTb = vT + (size_t)bh * 64 * 2048;

    // Q as B-fragments: 4 subtiles (q = q0 + w*64 + s*16 + l15), temp*log2e pre-folded
    bf16x8 bq[4][3];
#pragma unroll
    for (int s = 0; s < 4; s++) {
        const u16* qrow = qeb + (size_t)(q0 + w * 64 + s * 16 + l15) * 96;
#pragma unroll
        for (int ks = 0; ks < 3; ks++) bq[s][ks] = *(const bf16x8*)(qrow + ks * 32 + quad * 8);
    }

    f32x4 O[4][4];
    float l_part[4];
#pragma unroll
    for (int s = 0; s < 4; s++) {
        l_part[s] = 0.f;
#pragma unroll
        for (int dt = 0; dt < 4; dt++) O[s][dt] = (f32x4){0.f, 0.f, 0.f, 0.f};
    }

    const int srow = tid >> 1, half = tid & 1;  // staging: 2 threads per key/d row
    const int sh = srow & 7;
    u16* Pw[4];
#pragma unroll
    for (int s = 0; s < 4; s++) Pw[s] = Ps + (size_t)(w * 64 + s * 16 + l15) * 64;

    for (int kb = 0; kb < 2048; kb += 64) {
        // global prefetch: K row = 12 chunks (6/thread), V^T row = 8 chunks (4/thread)
        const u16* kg = keb + (size_t)(kb + srow) * 96;
        uint4 kx[6];
#pragma unroll
        for (int i = 0; i < 6; i++) kx[i] = *(const uint4*)(kg + (half * 6 + i) * 8);
        const u16* vg = vTb + (size_t)srow * 2048 + kb;
        uint4 vx[4];
#pragma unroll
        for (int i = 0; i < 4; i++) vx[i] = *(const uint4*)(vg + (half * 4 + i) * 8);
        __syncthreads();
#pragma unroll
        for (int i = 0; i < 6; i++)
            *(uint4*)(Ks + srow * 128 + (((half * 6 + i) ^ sh) & 15) * 8) = kx[i];
#pragma unroll
        for (int i = 0; i < 4; i++)
            *(uint4*)(Vt + srow * 64 + ((half * 4 + i) ^ sh) * 8) = vx[i];
        __syncthreads();

        // ---- St = K * Q^T : A-frags from Ks (keys on rows), B = bq ----
        f32x4 S[4][4];
#pragma unroll
        for (int s = 0; s < 4; s++)
#pragma unroll
            for (int nt = 0; nt < 4; nt++) S[s][nt] = (f32x4){0.f, 0.f, 0.f, 0.f};
#pragma unroll
        for (int ks = 0; ks < 3; ks++) {
            bf16x8 ak[4];
#pragma unroll
            for (int nt = 0; nt < 4; nt++)
                ak[nt] = *(const bf16x8*)(Ks + (nt * 16 + l15) * 128 + (((ks * 4 + quad) ^ lsw) & 15) * 8);
#pragma unroll
            for (int s = 0; s < 4; s++)
#pragma unroll
                for (int nt = 0; nt < 4; nt++)
                    S[s][nt] = __builtin_amdgcn_mfma_f32_16x16x32_bf16(ak[nt], bq[s][ks], S[s][nt], 0, 0, 0);
        }

        // ---- max-free softmax: p = exp2(s) (scores bounded, fp32-safe); l is per-lane partial ----
#pragma unroll
        for (int s = 0; s < 4; s++) {
            float sum = 0.f;
#pragma unroll
            for (int nt = 0; nt < 4; nt++)
#pragma unroll
                for (int r = 0; r < 4; r++) {
                    float p = __builtin_amdgcn_exp2f(S[s][nt][r]);
                    S[s][nt][r] = p;
                    sum += p;
                }
            l_part[s] += sum;
#pragma unroll
            for (int nt = 0; nt < 4; nt++) {
                int c = (nt * 2 + (quad >> 1)) ^ lsw;
                *(uint2*)(Pw[s] + c * 8 + (quad & 1) * 4) =
                    make_uint2(pack2(S[s][nt][0], S[s][nt][1]), pack2(S[s][nt][2], S[s][nt][3]));
            }
        }

        // ---- O^T += V^T * P^T (A = Vt frags, B = Ps frags; in-wave DS ordering) ----
#pragma unroll
        for (int kk = 0; kk < 2; kk++) {
            bf16x8 av[4];
#pragma unroll
            for (int dt = 0; dt < 4; dt++)
                av[dt] = *(const bf16x8*)(Vt + (dt * 16 + l15) * 64 + ((kk * 4 + quad) ^ lsw) * 8);
#pragma unroll
            for (int s = 0; s < 4; s++) {
                bf16x8 pb = *(const bf16x8*)(Pw[s] + ((kk * 4 + quad) ^ lsw) * 8);
#pragma unroll
                for (int dt = 0; dt < 4; dt++)
                    O[s][dt] = __builtin_amdgcn_mfma_f32_16x16x32_bf16(av[dt], pb, O[s][dt], 0, 0, 0);
            }
        }
    }

    // ---- epilogue: reduce l across quads once, divide, packed b64 stores ----
    const int b = bh >> 4, h = bh & 15;
#pragma unroll
    for (int s = 0; s < 4; s++) {
        float l = l_part[s];
        l += __shfl_xor(l, 16);
        l += __shfl_xor(l, 32);
        float linv = 1.0f / l;
        int tq = q0 + w * 64 + s * 16 + l15;
#pragma unroll
        for (int dt = 0; dt < 4; dt++) {
            int d = h * 64 + dt * 16 + quad * 4;
            *(uint2*)(out + (size_t)(b * 2048 + tq) * 1024 + d) =
                make_uint2(pack2(O[s][dt][0] * linv, O[s][dt][1] * linv),
                           pack2(O[s][dt][2] * linv, O[s][dt][3] * linv));
        }
    }
}

// ---------------- launch ----------------
extern "C" void kernel_launch(void* const* d_in, const int* in_sizes, int n_in,
                              void* d_out, int out_size, void* d_ws, size_t ws_size,
                              hipStream_t stream)
{
    (void)in_sizes; (void)n_in; (void)out_size; (void)ws_size;
    const float* x   = (const float*)d_in[0];
    const float* Wq  = (const float*)d_in[1];
    const float* bq  = (const float*)d_in[2];
    const float* Wk  = (const float*)d_in[3];
    const float* bk  = (const float*)d_in[4];
    const float* Wv  = (const float*)d_in[5];
    const float* bv  = (const float*)d_in[6];
    const float* Wo  = (const float*)d_in[7];
    const float* bo  = (const float*)d_in[8];
    const float* Wqs = (const float*)d_in[9];
    const float* bqs = (const float*)d_in[10];
    const float* Wks = (const float*)d_in[11];
    const float* bks = (const float*)d_in[12];
    const float* Wvs = (const float*)d_in[13];
    const float* bvs = (const float*)d_in[14];
    const float* temp = (const float*)d_in[15];

    char* ws = (char*)d_ws;
    u16* xb  = (u16*)(ws);                 // 8 MB (x bf16; reused as aob after gemm_qkv)
    u16* Wqb = (u16*)(ws + 8388608);       // 2 MB
    u16* Wkb = (u16*)(ws + 10485760);      // 2 MB
    u16* Wvb = (u16*)(ws + 12582912);      // 2 MB
    u16* Wob = (u16*)(ws + 14680064);      // 2 MB
    u16* qb  = (u16*)(ws + 16777216);      // 8 MB  [B,H,T,64]
    u16* kbq = (u16*)(ws + 25165824);      // 8 MB
    u16* vbq = (u16*)(ws + 33554432);      // 8 MB
    u16* qeb = (u16*)(ws + 41943040);      // 12 MB [B,H,T,96]
    u16* keb = (u16*)(ws + 54525952);      // 12 MB
    u16* vTb = (u16*)(ws + 67108864);      // 8 MB  [B,H,64,T]
    u16* aob = xb;                         // alias: xb dead after gemm_qkv

    cast_all_kernel<<<8192, 256, 0, stream>>>(x, Wq, Wk, Wv, Wo, xb, Wqb, Wkb, Wvb, Wob);
    gemm_qkv_kernel<<<dim3(8, 32, 3), 256, 0, stream>>>(xb, Wqb, Wkb, Wvb, bq, bk, bv, qb, kbq, vbq, vTb);
    build_ext_kernel<<<256, 256, 0, stream>>>(qb, kbq, vbq, Wqs, bqs, Wks, bks, Wvs, bvs, temp, qeb, keb);
    attn_kernel<<<dim3(16, 32), 128, 0, stream>>>(qeb, keb, vTb, aob);
    gemm_out_kernel<<<dim3(8, 32), 256, 0, stream>>>(aob, Wob, bo, (float*)d_out);
}

// Round 5
// 280.593 us; speedup vs baseline: 1.3894x; 1.3894x over previous
//
#include <hip/hip_runtime.h>
#include <stdint.h>

typedef unsigned short u16;
typedef unsigned int u32;
typedef __attribute__((ext_vector_type(8))) short bf16x8;
typedef __attribute__((ext_vector_type(4))) float f32x4;

__device__ __forceinline__ u16 f2b(float f) {
    union { float f; u32 u; } t; t.f = f;
    return (u16)((t.u + 0x7FFFu + ((t.u >> 16) & 1u)) >> 16);
}
__device__ __forceinline__ float b2f(u16 h) {
    union { u32 u; float f; } t; t.u = ((u32)h) << 16;
    return t.f;
}
__device__ __forceinline__ u32 pack2(float a, float b) {
    return (u32)f2b(a) | ((u32)f2b(b) << 16);
}

// ---------------- fused fp32 -> bf16 cast (x + 4 weights, one launch) ----------------
__global__ void cast_all_kernel(const float* __restrict__ x,
                                const float* __restrict__ Wq, const float* __restrict__ Wk,
                                const float* __restrict__ Wv, const float* __restrict__ Wo,
                                u16* __restrict__ xb, u16* __restrict__ Wqb, u16* __restrict__ Wkb,
                                u16* __restrict__ Wvb, u16* __restrict__ Wob) {
    int i = blockIdx.x * blockDim.x + threadIdx.x;  // float4 index, total 2097152
    const float* s; u16* d; int off;
    if (i < 1048576) { s = x; d = xb; off = i; }
    else {
        int j = i - 1048576;
        int w = j >> 18; off = j & 262143;
        if (w == 0) { s = Wq; d = Wqb; }
        else if (w == 1) { s = Wk; d = Wkb; }
        else if (w == 2) { s = Wv; d = Wvb; }
        else { s = Wo; d = Wob; }
    }
    float4 f = ((const float4*)s)[off];
    ((uint2*)d)[off] = make_uint2(pack2(f.x, f.y), pack2(f.z, f.w));
}

// ---------------- GEMM: y = A @ W^T + bias ----------------
#define GT 128
#define GK 32
#define GLD 40

template<int MODE>
__device__ __forceinline__ void gemm_core(
    const u16* __restrict__ A, const u16* __restrict__ W, const float* __restrict__ bias,
    u16* __restrict__ obf, u16* __restrict__ vtout, float* __restrict__ ofp)
{
    __shared__ u16 As[GT * GLD];
    __shared__ u16 Bs[GT * GLD];
    const int tid = threadIdx.x;
    const int lane = tid & 63, w = tid >> 6;
    const int wm = w >> 1, wn = w & 1;
    const int l15 = lane & 15, quad = lane >> 4;
    const int M0 = blockIdx.y * GT, N0 = blockIdx.x * GT;

    f32x4 acc[4][4];
#pragma unroll
    for (int i = 0; i < 4; i++)
#pragma unroll
        for (int j = 0; j < 4; j++) acc[i][j] = (f32x4){0.f, 0.f, 0.f, 0.f};

    const int srow = tid >> 1, shalf = tid & 1;
    const u16* Ag = A + (size_t)(M0 + srow) * 1024 + shalf * 16;
    const u16* Wg = W + (size_t)(N0 + srow) * 1024 + shalf * 16;
    u16* Asw = As + srow * GLD + shalf * 16;
    u16* Bsw = Bs + srow * GLD + shalf * 16;

    for (int k0 = 0; k0 < 1024; k0 += GK) {
        uint4 a0 = *(const uint4*)(Ag + k0);
        uint4 a1 = *(const uint4*)(Ag + k0 + 8);
        uint4 b0 = *(const uint4*)(Wg + k0);
        uint4 b1 = *(const uint4*)(Wg + k0 + 8);
        __syncthreads();
        *(uint4*)(Asw) = a0;
        *(uint4*)(Asw + 8) = a1;
        *(uint4*)(Bsw) = b0;
        *(uint4*)(Bsw + 8) = b1;
        __syncthreads();
        bf16x8 af[4], bf[4];
#pragma unroll
        for (int mi = 0; mi < 4; mi++)
            af[mi] = *(const bf16x8*)(As + (wm * 64 + mi * 16 + l15) * GLD + quad * 8);
#pragma unroll
        for (int ni = 0; ni < 4; ni++)
            bf[ni] = *(const bf16x8*)(Bs + (wn * 64 + ni * 16 + l15) * GLD + quad * 8);
#pragma unroll
        for (int mi = 0; mi < 4; mi++)
#pragma unroll
            for (int ni = 0; ni < 4; ni++)
                acc[mi][ni] = __builtin_amdgcn_mfma_f32_16x16x32_bf16(af[mi], bf[ni], acc[mi][ni], 0, 0, 0);
    }

#pragma unroll
    for (int mi = 0; mi < 4; mi++)
#pragma unroll
        for (int ni = 0; ni < 4; ni++) {
            int n = N0 + wn * 64 + ni * 16 + l15;
            float bias_n = bias[n];
            float vals[4];
#pragma unroll
            for (int r = 0; r < 4; r++)
                vals[r] = acc[mi][ni][r] + bias_n;
            int m0 = M0 + wm * 64 + mi * 16 + quad * 4;
            if (MODE == 0) {
                int b = m0 >> 11, t = m0 & 2047;
                int h = n >> 6, hd = n & 63;
#pragma unroll
                for (int r = 0; r < 4; r++)
                    obf[((size_t)((b * 16 + h) * 2048 + (t + r)) << 6) + hd] = f2b(vals[r]);
                if (vtout) {  // also emit V^T: [bh*64+hd][t], t fast => packed b64
                    *(uint2*)(vtout + ((size_t)((b * 16 + h) * 64 + hd)) * 2048 + t) =
                        make_uint2(pack2(vals[0], vals[1]), pack2(vals[2], vals[3]));
                }
            } else {
#pragma unroll
                for (int r = 0; r < 4; r++)
                    ofp[(size_t)(m0 + r) * 1024 + n] = vals[r];
            }
        }
}

__global__ __launch_bounds__(256) void gemm_qkv_kernel(
    const u16* __restrict__ xb,
    const u16* __restrict__ Wq, const u16* __restrict__ Wk, const u16* __restrict__ Wv,
    const float* __restrict__ bq, const float* __restrict__ bk, const float* __restrict__ bv,
    u16* __restrict__ q, u16* __restrict__ k, u16* __restrict__ v, u16* __restrict__ vT)
{
    const u16* W; const float* bias; u16* o; u16* vt = nullptr;
    if (blockIdx.z == 0)      { W = Wq; bias = bq; o = q; }
    else if (blockIdx.z == 1) { W = Wk; bias = bk; o = k; }
    else                      { W = Wv; bias = bv; o = v; vt = vT; }
    gemm_core<0>(xb, W, bias, o, vt, nullptr);
}

__global__ __launch_bounds__(256) void gemm_out_kernel(
    const u16* __restrict__ ao, const u16* __restrict__ Wo, const float* __restrict__ bo,
    float* __restrict__ out)
{
    gemm_core<1>(ao, Wo, bo, nullptr, nullptr, out);
}

// ---------------- build extended q/k rows (96 dims), temp*log2e folded into qe ----------------
__global__ void build_ext_kernel(
    const u16* __restrict__ q, const u16* __restrict__ k, const u16* __restrict__ v,
    const float* __restrict__ Wqs, const float* __restrict__ bqs,
    const float* __restrict__ Wks, const float* __restrict__ bks,
    const float* __restrict__ Wvs, const float* __restrict__ bvs,
    const float* __restrict__ temp_p,
    u16* __restrict__ qe, u16* __restrict__ ke)
{
    int row = blockIdx.x * blockDim.x + threadIdx.x;
    if (row >= 2 * 16 * 2048) return;
    const float temp = *temp_p * 1.44269504088896f;  // scores emerge in log2 domain
    const u16* qr = q + (size_t)row * 64;
    const u16* kr = k + (size_t)row * 64;
    const u16* vr = v + (size_t)row * 64;

    float qs0 = bqs[0], qs1 = bqs[1], qs2 = bqs[2];
    float ks0 = bks[0], ks1 = bks[1], ks2 = bks[2];
    float vs0 = bvs[0], vs1 = bvs[1], vs2 = bvs[2];
#pragma unroll
    for (int j = 0; j < 64; j += 8) {
        bf16x8 qv = *(const bf16x8*)(qr + j);
        bf16x8 kv = *(const bf16x8*)(kr + j);
        bf16x8 vv = *(const bf16x8*)(vr + j);
#pragma unroll
        for (int i = 0; i < 8; i++) {
            float qf = b2f((u16)qv[i]);
            float kf = b2f((u16)kv[i]);
            float vf = b2f((u16)vv[i]);
            qs0 += qf * Wqs[j + i]; qs1 += qf * Wqs[64 + j + i]; qs2 += qf * Wqs[128 + j + i];
            ks0 += kf * Wks[j + i]; ks1 += kf * Wks[64 + j + i]; ks2 += kf * Wks[128 + j + i];
            vs0 += vf * Wvs[j + i]; vs1 += vf * Wvs[64 + j + i]; vs2 += vf * Wvs[128 + j + i];
        }
    }
    float c0 = ks1 * vs2 - ks2 * vs1;
    float c1 = ks2 * vs0 - ks0 * vs2;
    float c2 = ks0 * vs1 - ks1 * vs0;

    u16* qer = qe + (size_t)row * 96;
    u16* ker = ke + (size_t)row * 96;
#pragma unroll
    for (int j = 0; j < 64; j += 8) {
        bf16x8 qv = *(const bf16x8*)(qr + j);
        bf16x8 sq;
#pragma unroll
        for (int i = 0; i < 8; i++) sq[i] = (short)f2b(b2f((u16)qv[i]) * temp);
        *(bf16x8*)(qer + j) = sq;
        *(bf16x8*)(ker + j) = *(const bf16x8*)(kr + j);
    }
    *(uint2*)(qer + 64) = make_uint2(pack2(qs0 * temp, qs1 * temp), (u32)f2b(qs2 * temp));
    *(uint2*)(ker + 64) = make_uint2(pack2(c0, c1), (u32)f2b(c2));
    uint2 z = make_uint2(0u, 0u);
#pragma unroll
    for (int j = 68; j < 96; j += 4) {
        *(uint2*)(qer + j) = z;
        *(uint2*)(ker + j) = z;
    }
}

// ---------------- flash attention: round-3 shape (4 waves x 2 subtiles, 256 thr)
// + max-free exp2 softmax. XOR-swizzled b128 LDS. ----------------
// Ks: [key 0..63][16B chunks, stride 16, 12 used]  16 KB
// Vt: [d 0..63][8 chunks]                           8 KB
// Ps: [q 0..127][8 chunks]                         16 KB (wave-private rows, no barrier)
__global__ __launch_bounds__(256) void attn_kernel(
    const u16* __restrict__ qe, const u16* __restrict__ ke, const u16* __restrict__ vT,
    u16* __restrict__ out)
{
    __shared__ u16 Ks[64 * 128];
    __shared__ u16 Vt[64 * 64];
    __shared__ u16 Ps[128 * 64];

    const int tid = threadIdx.x;
    const int lane = tid & 63, w = tid >> 6;
    const int l15 = lane & 15, quad = lane >> 4;
    const int lsw = l15 & 7;
    const int bh = blockIdx.y;
    const int q0 = blockIdx.x * 128;

    const u16* qeb = qe + (size_t)bh * 2048 * 96;
    const u16* keb = ke + (size_t)bh * 2048 * 96;
    const u16* vTb = vT + (size_t)bh * 64 * 2048;

    // Q as B-fragments (q = q0 + w*32 + s*16 + l15), temp*log2e pre-folded
    bf16x8 bq[2][3];
#pragma unroll
    for (int s = 0; s < 2; s++) {
        const u16* qrow = qeb + (size_t)(q0 + w * 32 + s * 16 + l15) * 96;
#pragma unroll
        for (int ks = 0; ks < 3; ks++) bq[s][ks] = *(const bf16x8*)(qrow + ks * 32 + quad * 8);
    }

    f32x4 O[2][4];
    float l_part[2];
#pragma unroll
    for (int s = 0; s < 2; s++) {
        l_part[s] = 0.f;
#pragma unroll
        for (int dt = 0; dt < 4; dt++) O[s][dt] = (f32x4){0.f, 0.f, 0.f, 0.f};
    }

    const int srow = tid >> 2, spart = tid & 3;  // staging: 4 threads per key/d row
    const int sh = srow & 7;
    u16* Pw[2];
#pragma unroll
    for (int s = 0; s < 2; s++) Pw[s] = Ps + (size_t)(w * 32 + s * 16 + l15) * 64;

    for (int kb = 0; kb < 2048; kb += 64) {
        const u16* kg = keb + (size_t)(kb + srow) * 96;
        uint4 kx0 = *(const uint4*)(kg + spart * 8);
        uint4 kx1 = *(const uint4*)(kg + (spart + 4) * 8);
        uint4 kx2 = *(const uint4*)(kg + (spart + 8) * 8);
        const u16* vg = vTb + (size_t)srow * 2048 + kb;
        uint4 vx0 = *(const uint4*)(vg + spart * 8);
        uint4 vx1 = *(const uint4*)(vg + (spart + 4) * 8);
        __syncthreads();
        *(uint4*)(Ks + srow * 128 + ((spart    ) ^ sh) * 8) = kx0;
        *(uint4*)(Ks + srow * 128 + ((spart + 4) ^ sh) * 8) = kx1;
        *(uint4*)(Ks + srow * 128 + ((spart + 8) ^ sh) * 8) = kx2;
        *(uint4*)(Vt + srow * 64 + ((spart    ) ^ sh) * 8) = vx0;
        *(uint4*)(Vt + srow * 64 + ((spart + 4) ^ sh) * 8) = vx1;
        __syncthreads();

        // ---- St = K * Q^T : A-frags from Ks (keys on rows), B = bq ----
        f32x4 S[2][4];
#pragma unroll
        for (int s = 0; s < 2; s++)
#pragma unroll
            for (int nt = 0; nt < 4; nt++) S[s][nt] = (f32x4){0.f, 0.f, 0.f, 0.f};
#pragma unroll
        for (int ks = 0; ks < 3; ks++) {
            bf16x8 ak[4];
#pragma unroll
            for (int nt = 0; nt < 4; nt++)
                ak[nt] = *(const bf16x8*)(Ks + (nt * 16 + l15) * 128 + (((ks * 4 + quad) ^ lsw) & 15) * 8);
#pragma unroll
            for (int s = 0; s < 2; s++)
#pragma unroll
                for (int nt = 0; nt < 4; nt++)
                    S[s][nt] = __builtin_amdgcn_mfma_f32_16x16x32_bf16(ak[nt], bq[s][ks], S[s][nt], 0, 0, 0);
        }

        // ---- max-free softmax: p = exp2(s) (scores bounded, fp32-safe); l per-lane partial ----
#pragma unroll
        for (int s = 0; s < 2; s++) {
            float sum = 0.f;
#pragma unroll
            for (int nt = 0; nt < 4; nt++)
#pragma unroll
                for (int r = 0; r < 4; r++) {
                    float p = __builtin_amdgcn_exp2f(S[s][nt][r]);
                    S[s][nt][r] = p;
                    sum += p;
                }
            l_part[s] += sum;
            // P^T rows: 4 consecutive keys per lane -> packed b64, swizzled chunk
#pragma unroll
            for (int nt = 0; nt < 4; nt++) {
                int c = (nt * 2 + (quad >> 1)) ^ lsw;
                *(uint2*)(Pw[s] + c * 8 + (quad & 1) * 4) =
                    make_uint2(pack2(S[s][nt][0], S[s][nt][1]), pack2(S[s][nt][2], S[s][nt][3]));
            }
        }

        // ---- O^T += V^T * P^T (A = Vt frags, B = Ps frags; in-wave DS ordering) ----
#pragma unroll
        for (int kk = 0; kk < 2; kk++) {
            bf16x8 av[4];
#pragma unroll
            for (int dt = 0; dt < 4; dt++)
                av[dt] = *(const bf16x8*)(Vt + (dt * 16 + l15) * 64 + ((kk * 4 + quad) ^ lsw) * 8);
#pragma unroll
            for (int s = 0; s < 2; s++) {
                bf16x8 pb = *(const bf16x8*)(Pw[s] + ((kk * 4 + quad) ^ lsw) * 8);
#pragma unroll
                for (int dt = 0; dt < 4; dt++)
                    O[s][dt] = __builtin_amdgcn_mfma_f32_16x16x32_bf16(av[dt], pb, O[s][dt], 0, 0, 0);
            }
        }
    }

    // ---- epilogue: reduce l across quads once, divide, packed b64 stores ----
    const int b = bh >> 4, h = bh & 15;
#pragma unroll
    for (int s = 0; s < 2; s++) {
        float l = l_part[s];
        l += __shfl_xor(l, 16);
        l += __shfl_xor(l, 32);
        float linv = 1.0f / l;
        int tq = q0 + w * 32 + s * 16 + l15;
#pragma unroll
        for (int dt = 0; dt < 4; dt++) {
            int d = h * 64 + dt * 16 + quad * 4;
            *(uint2*)(out + (size_t)(b * 2048 + tq) * 1024 + d) =
                make_uint2(pack2(O[s][dt][0] * linv, O[s][dt][1] * linv),
                           pack2(O[s][dt][2] * linv, O[s][dt][3] * linv));
        }
    }
}

// ---------------- launch ----------------
extern "C" void kernel_launch(void* const* d_in, const int* in_sizes, int n_in,
                              void* d_out, int out_size, void* d_ws, size_t ws_size,
                              hipStream_t stream)
{
    (void)in_sizes; (void)n_in; (void)out_size; (void)ws_size;
    const float* x   = (const float*)d_in[0];
    const float* Wq  = (const float*)d_in[1];
    const float* bq  = (const float*)d_in[2];
    const float* Wk  = (const float*)d_in[3];
    const float* bk  = (const float*)d_in[4];
    const float* Wv  = (const float*)d_in[5];
    const float* bv  = (const float*)d_in[6];
    const float* Wo  = (const float*)d_in[7];
    const float* bo  = (const float*)d_in[8];
    const float* Wqs = (const float*)d_in[9];
    const float* bqs = (const float*)d_in[10];
    const float* Wks = (const float*)d_in[11];
    const float* bks = (const float*)d_in[12];
    const float* Wvs = (const float*)d_in[13];
    const float* bvs = (const float*)d_in[14];
    const float* temp = (const float*)d_in[15];

    char* ws = (char*)d_ws;
    u16* xb  = (u16*)(ws);                 // 8 MB (x bf16; reused as aob after gemm_qkv)
    u16* Wqb = (u16*)(ws + 8388608);       // 2 MB
    u16* Wkb = (u16*)(ws + 10485760);      // 2 MB
    u16* Wvb = (u16*)(ws + 12582912);      // 2 MB
    u16* Wob = (u16*)(ws + 14680064);      // 2 MB
    u16* qb  = (u16*)(ws + 16777216);      // 8 MB  [B,H,T,64]
    u16* kbq = (u16*)(ws + 25165824);      // 8 MB
    u16* vbq = (u16*)(ws + 33554432);      // 8 MB
    u16* qeb = (u16*)(ws + 41943040);      // 12 MB [B,H,T,96]
    u16* keb = (u16*)(ws + 54525952);      // 12 MB
    u16* vTb = (u16*)(ws + 67108864);      // 8 MB  [B,H,64,T]
    u16* aob = xb;                         // alias: xb dead after gemm_qkv

    cast_all_kernel<<<8192, 256, 0, stream>>>(x, Wq, Wk, Wv, Wo, xb, Wqb, Wkb, Wvb, Wob);
    gemm_qkv_kernel<<<dim3(8, 32, 3), 256, 0, stream>>>(xb, Wqb, Wkb, Wvb, bq, bk, bv, qb, kbq, vbq, vTb);
    build_ext_kernel<<<256, 256, 0, stream>>>(qb, kbq, vbq, Wqs, bqs, Wks, bks, Wvs, bvs, temp, qeb, keb);
    attn_kernel<<<dim3(16, 32), 256, 0, stream>>>(qeb, keb, vTb, aob);
    gemm_out_kernel<<<dim3(8, 32), 256, 0, stream>>>(aob, Wob, bo, (float*)d_out);
}

// Round 6
// 253.418 us; speedup vs baseline: 1.5384x; 1.1072x over previous
//
#include <hip/hip_runtime.h>
#include <stdint.h>

typedef unsigned short u16;
typedef unsigned int u32;
typedef __attribute__((ext_vector_type(8))) short bf16x8;
typedef __attribute__((ext_vector_type(4))) float f32x4;

__device__ __forceinline__ u16 f2b(float f) {
    union { float f; u32 u; } t; t.f = f;
    return (u16)((t.u + 0x7FFFu + ((t.u >> 16) & 1u)) >> 16);
}
__device__ __forceinline__ float b2f(u16 h) {
    union { u32 u; float f; } t; t.u = ((u32)h) << 16;
    return t.f;
}
__device__ __forceinline__ u32 pack2(float a, float b) {
    return (u32)f2b(a) | ((u32)f2b(b) << 16);
}

// async global->LDS 16B copy: per-lane global addr, wave-uniform LDS base + lane*16
__device__ __forceinline__ void async_cp16(const u16* g, const u16* lds_base) {
    __builtin_amdgcn_global_load_lds(
        (const __attribute__((address_space(1))) void*)(uintptr_t)g,
        (__attribute__((address_space(3))) void*)(u32)(uintptr_t)lds_base,
        16, 0, 0);
}

// ---------------- fused fp32 -> bf16 cast (x + 4 weights, one launch) ----------------
__global__ void cast_all_kernel(const float* __restrict__ x,
                                const float* __restrict__ Wq, const float* __restrict__ Wk,
                                const float* __restrict__ Wv, const float* __restrict__ Wo,
                                u16* __restrict__ xb, u16* __restrict__ Wqb, u16* __restrict__ Wkb,
                                u16* __restrict__ Wvb, u16* __restrict__ Wob) {
    int i = blockIdx.x * blockDim.x + threadIdx.x;  // float4 index, total 2097152
    const float* s; u16* d; int off;
    if (i < 1048576) { s = x; d = xb; off = i; }
    else {
        int j = i - 1048576;
        int w = j >> 18; off = j & 262143;
        if (w == 0) { s = Wq; d = Wqb; }
        else if (w == 1) { s = Wk; d = Wkb; }
        else if (w == 2) { s = Wv; d = Wvb; }
        else { s = Wo; d = Wob; }
    }
    float4 f = ((const float4*)s)[off];
    ((uint2*)d)[off] = make_uint2(pack2(f.x, f.y), pack2(f.z, f.w));
}

// ---------------- GEMM: y = A @ W^T + bias ----------------
// m97-style: global_load_lds width-16 staging, unpadded 128x32 LDS tiles with
// global-side XOR chunk swizzle (gchunk = chunk ^ (row&3)) so b128 frag reads
// are conflict-free (8 lanes per 4-bank group = b128 minimum).
#define GT 128
#define GK 32

template<int MODE>
__device__ __forceinline__ void gemm_core(
    const u16* __restrict__ A, const u16* __restrict__ W, const float* __restrict__ bias,
    u16* __restrict__ obf, u16* __restrict__ vtout, float* __restrict__ ofp)
{
    __shared__ __align__(16) u16 As[GT * GK];
    __shared__ __align__(16) u16 Bs[GT * GK];
    const int tid = threadIdx.x;
    const int lane = tid & 63, w = tid >> 6;
    const int wm = w >> 1, wn = w & 1;
    const int l15 = lane & 15, quad = lane >> 4;
    const int M0 = blockIdx.y * GT, N0 = blockIdx.x * GT;

    f32x4 acc[4][4];
#pragma unroll
    for (int i = 0; i < 4; i++)
#pragma unroll
        for (int j = 0; j < 4; j++) acc[i][j] = (f32x4){0.f, 0.f, 0.f, 0.f};

    // staging geometry: unit u in [0,512), 16B each; row = u>>2, lchunk = u&3,
    // global chunk = lchunk ^ (row&3). Wave w covers u in [w*128, w*128+128).
    int ua = w * 128 + lane;          // first A/B unit this lane (j=0)
    int r0 = ua >> 2, c0 = ((ua & 3) ^ (r0 & 3)) * 8;
    int ub = ua + 64;                 // second unit (j=1)
    int r1 = ub >> 2, c1 = ((ub & 3) ^ (r1 & 3)) * 8;
    const u16* Ag0 = A + (size_t)(M0 + r0) * 1024 + c0;
    const u16* Ag1 = A + (size_t)(M0 + r1) * 1024 + c1;
    const u16* Wg0 = W + (size_t)(N0 + r0) * 1024 + c0;
    const u16* Wg1 = W + (size_t)(N0 + r1) * 1024 + c1;
    const u16* As0 = As + (w * 128) * 8;       // wave-uniform LDS bases
    const u16* As1 = As + (w * 128 + 64) * 8;
    const u16* Bs0 = Bs + (w * 128) * 8;
    const u16* Bs1 = Bs + (w * 128 + 64) * 8;

    for (int k0 = 0; k0 < 1024; k0 += GK) {
        __syncthreads();  // all waves done reading previous tile
        async_cp16(Ag0 + k0, As0);
        async_cp16(Ag1 + k0, As1);
        async_cp16(Wg0 + k0, Bs0);
        async_cp16(Wg1 + k0, Bs1);
        __syncthreads();  // vmcnt drained: staged data visible

        bf16x8 af[4], bf[4];
#pragma unroll
        for (int mi = 0; mi < 4; mi++)
            af[mi] = *(const bf16x8*)(As + (wm * 64 + mi * 16 + l15) * 32 + ((quad ^ (l15 & 3)) * 8));
#pragma unroll
        for (int ni = 0; ni < 4; ni++)
            bf[ni] = *(const bf16x8*)(Bs + (wn * 64 + ni * 16 + l15) * 32 + ((quad ^ (l15 & 3)) * 8));
#pragma unroll
        for (int mi = 0; mi < 4; mi++)
#pragma unroll
            for (int ni = 0; ni < 4; ni++)
                acc[mi][ni] = __builtin_amdgcn_mfma_f32_16x16x32_bf16(af[mi], bf[ni], acc[mi][ni], 0, 0, 0);
    }

#pragma unroll
    for (int mi = 0; mi < 4; mi++)
#pragma unroll
        for (int ni = 0; ni < 4; ni++) {
            int n = N0 + wn * 64 + ni * 16 + l15;
            float bias_n = bias[n];
            float vals[4];
#pragma unroll
            for (int r = 0; r < 4; r++)
                vals[r] = acc[mi][ni][r] + bias_n;
            int m0 = M0 + wm * 64 + mi * 16 + quad * 4;
            if (MODE == 0) {
                int b = m0 >> 11, t = m0 & 2047;
                int h = n >> 6, hd = n & 63;
#pragma unroll
                for (int r = 0; r < 4; r++)
                    obf[((size_t)((b * 16 + h) * 2048 + (t + r)) << 6) + hd] = f2b(vals[r]);
                if (vtout) {  // also emit V^T: [bh*64+hd][t], t fast => packed b64
                    *(uint2*)(vtout + ((size_t)((b * 16 + h) * 64 + hd)) * 2048 + t) =
                        make_uint2(pack2(vals[0], vals[1]), pack2(vals[2], vals[3]));
                }
            } else {
#pragma unroll
                for (int r = 0; r < 4; r++)
                    ofp[(size_t)(m0 + r) * 1024 + n] = vals[r];
            }
        }
}

__global__ __launch_bounds__(256) void gemm_qkv_kernel(
    const u16* __restrict__ xb,
    const u16* __restrict__ Wq, const u16* __restrict__ Wk, const u16* __restrict__ Wv,
    const float* __restrict__ bq, const float* __restrict__ bk, const float* __restrict__ bv,
    u16* __restrict__ q, u16* __restrict__ k, u16* __restrict__ v, u16* __restrict__ vT)
{
    const u16* W; const float* bias; u16* o; u16* vt = nullptr;
    if (blockIdx.z == 0)      { W = Wq; bias = bq; o = q; }
    else if (blockIdx.z == 1) { W = Wk; bias = bk; o = k; }
    else                      { W = Wv; bias = bv; o = v; vt = vT; }
    gemm_core<0>(xb, W, bias, o, vt, nullptr);
}

__global__ __launch_bounds__(256) void gemm_out_kernel(
    const u16* __restrict__ ao, const u16* __restrict__ Wo, const float* __restrict__ bo,
    float* __restrict__ out)
{
    gemm_core<1>(ao, Wo, bo, nullptr, nullptr, out);
}

// ---------------- build extended q/k rows (96 dims), temp*log2e folded into qe ----------------
__global__ void build_ext_kernel(
    const u16* __restrict__ q, const u16* __restrict__ k, const u16* __restrict__ v,
    const float* __restrict__ Wqs, const float* __restrict__ bqs,
    const float* __restrict__ Wks, const float* __restrict__ bks,
    const float* __restrict__ Wvs, const float* __restrict__ bvs,
    const float* __restrict__ temp_p,
    u16* __restrict__ qe, u16* __restrict__ ke)
{
    int row = blockIdx.x * blockDim.x + threadIdx.x;
    if (row >= 2 * 16 * 2048) return;
    const float temp = *temp_p * 1.44269504088896f;  // scores emerge in log2 domain
    const u16* qr = q + (size_t)row * 64;
    const u16* kr = k + (size_t)row * 64;
    const u16* vr = v + (size_t)row * 64;

    float qs0 = bqs[0], qs1 = bqs[1], qs2 = bqs[2];
    float ks0 = bks[0], ks1 = bks[1], ks2 = bks[2];
    float vs0 = bvs[0], vs1 = bvs[1], vs2 = bvs[2];
#pragma unroll
    for (int j = 0; j < 64; j += 8) {
        bf16x8 qv = *(const bf16x8*)(qr + j);
        bf16x8 kv = *(const bf16x8*)(kr + j);
        bf16x8 vv = *(const bf16x8*)(vr + j);
#pragma unroll
        for (int i = 0; i < 8; i++) {
            float qf = b2f((u16)qv[i]);
            float kf = b2f((u16)kv[i]);
            float vf = b2f((u16)vv[i]);
            qs0 += qf * Wqs[j + i]; qs1 += qf * Wqs[64 + j + i]; qs2 += qf * Wqs[128 + j + i];
            ks0 += kf * Wks[j + i]; ks1 += kf * Wks[64 + j + i]; ks2 += kf * Wks[128 + j + i];
            vs0 += vf * Wvs[j + i]; vs1 += vf * Wvs[64 + j + i]; vs2 += vf * Wvs[128 + j + i];
        }
    }
    float c0 = ks1 * vs2 - ks2 * vs1;
    float c1 = ks2 * vs0 - ks0 * vs2;
    float c2 = ks0 * vs1 - ks1 * vs0;

    u16* qer = qe + (size_t)row * 96;
    u16* ker = ke + (size_t)row * 96;
#pragma unroll
    for (int j = 0; j < 64; j += 8) {
        bf16x8 qv = *(const bf16x8*)(qr + j);
        bf16x8 sq;
#pragma unroll
        for (int i = 0; i < 8; i++) sq[i] = (short)f2b(b2f((u16)qv[i]) * temp);
        *(bf16x8*)(qer + j) = sq;
        *(bf16x8*)(ker + j) = *(const bf16x8*)(kr + j);
    }
    *(uint2*)(qer + 64) = make_uint2(pack2(qs0 * temp, qs1 * temp), (u32)f2b(qs2 * temp));
    *(uint2*)(ker + 64) = make_uint2(pack2(c0, c1), (u32)f2b(c2));
    uint2 z = make_uint2(0u, 0u);
#pragma unroll
    for (int j = 68; j < 96; j += 4) {
        *(uint2*)(qer + j) = z;
        *(uint2*)(ker + j) = z;
    }
}

// ---------------- flash attention: round-3 shape (4 waves x 2 subtiles, 256 thr)
// + max-free exp2 softmax. XOR-swizzled b128 LDS. ----------------
// Ks: [key 0..63][16B chunks, stride 16, 12 used]  16 KB
// Vt: [d 0..63][8 chunks]                           8 KB
// Ps: [q 0..127][8 chunks]                         16 KB (wave-private rows, no barrier)
__global__ __launch_bounds__(256) void attn_kernel(
    const u16* __restrict__ qe, const u16* __restrict__ ke, const u16* __restrict__ vT,
    u16* __restrict__ out)
{
    __shared__ __align__(16) u16 Ks[64 * 128];
    __shared__ __align__(16) u16 Vt[64 * 64];
    __shared__ __align__(16) u16 Ps[128 * 64];

    const int tid = threadIdx.x;
    const int lane = tid & 63, w = tid >> 6;
    const int l15 = lane & 15, quad = lane >> 4;
    const int lsw = l15 & 7;
    const int bh = blockIdx.y;
    const int q0 = blockIdx.x * 128;

    const u16* qeb = qe + (size_t)bh * 2048 * 96;
    const u16* keb = ke + (size_t)bh * 2048 * 96;
    const u16* vTb = vT + (size_t)bh * 64 * 2048;

    // Q as B-fragments (q = q0 + w*32 + s*16 + l15), temp*log2e pre-folded
    bf16x8 bq[2][3];
#pragma unroll
    for (int s = 0; s < 2; s++) {
        const u16* qrow = qeb + (size_t)(q0 + w * 32 + s * 16 + l15) * 96;
#pragma unroll
        for (int ks = 0; ks < 3; ks++) bq[s][ks] = *(const bf16x8*)(qrow + ks * 32 + quad * 8);
    }

    f32x4 O[2][4];
    float l_part[2];
#pragma unroll
    for (int s = 0; s < 2; s++) {
        l_part[s] = 0.f;
#pragma unroll
        for (int dt = 0; dt < 4; dt++) O[s][dt] = (f32x4){0.f, 0.f, 0.f, 0.f};
    }

    const int srow = tid >> 2, spart = tid & 3;  // staging: 4 threads per key/d row
    const int sh = srow & 7;
    u16* Pw[2];
#pragma unroll
    for (int s = 0; s < 2; s++) Pw[s] = Ps + (size_t)(w * 32 + s * 16 + l15) * 64;

    for (int kb = 0; kb < 2048; kb += 64) {
        const u16* kg = keb + (size_t)(kb + srow) * 96;
        uint4 kx0 = *(const uint4*)(kg + spart * 8);
        uint4 kx1 = *(const uint4*)(kg + (spart + 4) * 8);
        uint4 kx2 = *(const uint4*)(kg + (spart + 8) * 8);
        const u16* vg = vTb + (size_t)srow * 2048 + kb;
        uint4 vx0 = *(const uint4*)(vg + spart * 8);
        uint4 vx1 = *(const uint4*)(vg + (spart + 4) * 8);
        __syncthreads();
        *(uint4*)(Ks + srow * 128 + ((spart    ) ^ sh) * 8) = kx0;
        *(uint4*)(Ks + srow * 128 + ((spart + 4) ^ sh) * 8) = kx1;
        *(uint4*)(Ks + srow * 128 + ((spart + 8) ^ sh) * 8) = kx2;
        *(uint4*)(Vt + srow * 64 + ((spart    ) ^ sh) * 8) = vx0;
        *(uint4*)(Vt + srow * 64 + ((spart + 4) ^ sh) * 8) = vx1;
        __syncthreads();

        // ---- St = K * Q^T : A-frags from Ks (keys on rows), B = bq ----
        f32x4 S[2][4];
#pragma unroll
        for (int s = 0; s < 2; s++)
#pragma unroll
            for (int nt = 0; nt < 4; nt++) S[s][nt] = (f32x4){0.f, 0.f, 0.f, 0.f};
#pragma unroll
        for (int ks = 0; ks < 3; ks++) {
            bf16x8 ak[4];
#pragma unroll
            for (int nt = 0; nt < 4; nt++)
                ak[nt] = *(const bf16x8*)(Ks + (nt * 16 + l15) * 128 + (((ks * 4 + quad) ^ lsw) & 15) * 8);
#pragma unroll
            for (int s = 0; s < 2; s++)
#pragma unroll
                for (int nt = 0; nt < 4; nt++)
                    S[s][nt] = __builtin_amdgcn_mfma_f32_16x16x32_bf16(ak[nt], bq[s][ks], S[s][nt], 0, 0, 0);
        }

        // ---- max-free softmax: p = exp2(s) (scores bounded, fp32-safe); l per-lane partial ----
#pragma unroll
        for (int s = 0; s < 2; s++) {
            float sum = 0.f;
#pragma unroll
            for (int nt = 0; nt < 4; nt++)
#pragma unroll
                for (int r = 0; r < 4; r++) {
                    float p = __builtin_amdgcn_exp2f(S[s][nt][r]);
                    S[s][nt][r] = p;
                    sum += p;
                }
            l_part[s] += sum;
            // P^T rows: 4 consecutive keys per lane -> packed b64, swizzled chunk
#pragma unroll
            for (int nt = 0; nt < 4; nt++) {
                int c = (nt * 2 + (quad >> 1)) ^ lsw;
                *(uint2*)(Pw[s] + c * 8 + (quad & 1) * 4) =
                    make_uint2(pack2(S[s][nt][0], S[s][nt][1]), pack2(S[s][nt][2], S[s][nt][3]));
            }
        }

        // ---- O^T += V^T * P^T (A = Vt frags, B = Ps frags; in-wave DS ordering) ----
#pragma unroll
        for (int kk = 0; kk < 2; kk++) {
            bf16x8 av[4];
#pragma unroll
            for (int dt = 0; dt < 4; dt++)
                av[dt] = *(const bf16x8*)(Vt + (dt * 16 + l15) * 64 + ((kk * 4 + quad) ^ lsw) * 8);
#pragma unroll
            for (int s = 0; s < 2; s++) {
                bf16x8 pb = *(const bf16x8*)(Pw[s] + ((kk * 4 + quad) ^ lsw) * 8);
#pragma unroll
                for (int dt = 0; dt < 4; dt++)
                    O[s][dt] = __builtin_amdgcn_mfma_f32_16x16x32_bf16(av[dt], pb, O[s][dt], 0, 0, 0);
            }
        }
    }

    // ---- epilogue: reduce l across quads once, divide, packed b64 stores ----
    const int b = bh >> 4, h = bh & 15;
#pragma unroll
    for (int s = 0; s < 2; s++) {
        float l = l_part[s];
        l += __shfl_xor(l, 16);
        l += __shfl_xor(l, 32);
        float linv = 1.0f / l;
        int tq = q0 + w * 32 + s * 16 + l15;
#pragma unroll
        for (int dt = 0; dt < 4; dt++) {
            int d = h * 64 + dt * 16 + quad * 4;
            *(uint2*)(out + (size_t)(b * 2048 + tq) * 1024 + d) =
                make_uint2(pack2(O[s][dt][0] * linv, O[s][dt][1] * linv),
                           pack2(O[s][dt][2] * linv, O[s][dt][3] * linv));
        }
    }
}

// ---------------- launch ----------------
extern "C" void kernel_launch(void* const* d_in, const int* in_sizes, int n_in,
                              void* d_out, int out_size, void* d_ws, size_t ws_size,
                              hipStream_t stream)
{
    (void)in_sizes; (void)n_in; (void)out_size; (void)ws_size;
    const float* x   = (const float*)d_in[0];
    const float* Wq  = (const float*)d_in[1];
    const float* bq  = (const float*)d_in[2];
    const float* Wk  = (const float*)d_in[3];
    const float* bk  = (const float*)d_in[4];
    const float* Wv  = (const float*)d_in[5];
    const float* bv  = (const float*)d_in[6];
    const float* Wo  = (const float*)d_in[7];
    const float* bo  = (const float*)d_in[8];
    const float* Wqs = (const float*)d_in[9];
    const float* bqs = (const float*)d_in[10];
    const float* Wks = (const float*)d_in[11];
    const float* bks = (const float*)d_in[12];
    const float* Wvs = (const float*)d_in[13];
    const float* bvs = (const float*)d_in[14];
    const float* temp = (const float*)d_in[15];

    char* ws = (char*)d_ws;
    u16* xb  = (u16*)(ws);                 // 8 MB (x bf16; reused as aob after gemm_qkv)
    u16* Wqb = (u16*)(ws + 8388608);       // 2 MB
    u16* Wkb = (u16*)(ws + 10485760);      // 2 MB
    u16* Wvb = (u16*)(ws + 12582912);      // 2 MB
    u16* Wob = (u16*)(ws + 14680064);      // 2 MB
    u16* qb  = (u16*)(ws + 16777216);      // 8 MB  [B,H,T,64]
    u16* kbq = (u16*)(ws + 25165824);      // 8 MB
    u16* vbq = (u16*)(ws + 33554432);      // 8 MB
    u16* qeb = (u16*)(ws + 41943040);      // 12 MB [B,H,T,96]
    u16* keb = (u16*)(ws + 54525952);      // 12 MB
    u16* vTb = (u16*)(ws + 67108864);      // 8 MB  [B,H,64,T]
    u16* aob = xb;                         // alias: xb dead after gemm_qkv

    cast_all_kernel<<<8192, 256, 0, stream>>>(x, Wq, Wk, Wv, Wo, xb, Wqb, Wkb, Wvb, Wob);
    gemm_qkv_kernel<<<dim3(8, 32, 3), 256, 0, stream>>>(xb, Wqb, Wkb, Wvb, bq, bk, bv, qb, kbq, vbq, vTb);
    build_ext_kernel<<<256, 256, 0, stream>>>(qb, kbq, vbq, Wqs, bqs, Wks, bks, Wvs, bvs, temp, qeb, keb);
    attn_kernel<<<dim3(16, 32), 256, 0, stream>>>(qeb, keb, vTb, aob);
    gemm_out_kernel<<<dim3(8, 32), 256, 0, stream>>>(aob, Wob, bo, (float*)d_out);
}

// Round 7
// 249.039 us; speedup vs baseline: 1.5654x; 1.0176x over previous
//
#include <hip/hip_runtime.h>
#include <stdint.h>

typedef unsigned short u16;
typedef unsigned int u32;
typedef __attribute__((ext_vector_type(8))) short bf16x8;
typedef __attribute__((ext_vector_type(4))) float f32x4;

__device__ __forceinline__ u16 f2b(float f) {
    union { float f; u32 u; } t; t.f = f;
    return (u16)((t.u + 0x7FFFu + ((t.u >> 16) & 1u)) >> 16);
}
__device__ __forceinline__ u32 pack2(float a, float b) {
    return (u32)f2b(a) | ((u32)f2b(b) << 16);
}

// async global->LDS 16B copy: per-lane global addr, wave-uniform LDS base + lane*16
__device__ __forceinline__ void async_cp16(const u16* g, const u16* lds_base) {
    __builtin_amdgcn_global_load_lds(
        (const __attribute__((address_space(1))) void*)(uintptr_t)g,
        (__attribute__((address_space(3))) void*)(u32)(uintptr_t)lds_base,
        16, 0, 0);
}

// ---------------- fused fp32 -> bf16 cast (x + 4 weights, one launch) ----------------
__global__ void cast_all_kernel(const float* __restrict__ x,
                                const float* __restrict__ Wq, const float* __restrict__ Wk,
                                const float* __restrict__ Wv, const float* __restrict__ Wo,
                                u16* __restrict__ xb, u16* __restrict__ Wqb, u16* __restrict__ Wkb,
                                u16* __restrict__ Wvb, u16* __restrict__ Wob) {
    int i = blockIdx.x * blockDim.x + threadIdx.x;  // float4 index, total 2097152
    const float* s; u16* d; int off;
    if (i < 1048576) { s = x; d = xb; off = i; }
    else {
        int j = i - 1048576;
        int w = j >> 18; off = j & 262143;
        if (w == 0) { s = Wq; d = Wqb; }
        else if (w == 1) { s = Wk; d = Wkb; }
        else if (w == 2) { s = Wv; d = Wvb; }
        else { s = Wo; d = Wob; }
    }
    float4 f = ((const float4*)s)[off];
    ((uint2*)d)[off] = make_uint2(pack2(f.x, f.y), pack2(f.z, f.w));
}

// ---------------- fused QKV GEMM + STP projections + qe/ke/vT emission ----------------
// 128x128 tiles, global_load_lds staging, XOR chunk swizzle.
// z=0: qe rows [0:96] complete (temp*log2e folded), z=1: ke[0:64] + k3 side,
// z=2: vT [B,H,64,T] + v3 side.
__global__ __launch_bounds__(256) void gemm_qkv_kernel(
    const u16* __restrict__ xb,
    const u16* __restrict__ Wq, const u16* __restrict__ Wk, const u16* __restrict__ Wv,
    const float* __restrict__ bq, const float* __restrict__ bk, const float* __restrict__ bv,
    const float* __restrict__ Wqs, const float* __restrict__ bqs,
    const float* __restrict__ Wks, const float* __restrict__ bks,
    const float* __restrict__ Wvs, const float* __restrict__ bvs,
    const float* __restrict__ temp_p,
    u16* __restrict__ qe, u16* __restrict__ ke, u16* __restrict__ vT,
    float4* __restrict__ k3b, float4* __restrict__ v3b)
{
    __shared__ __align__(16) u16 As[128 * 32];
    __shared__ __align__(16) u16 Bs[128 * 32];
    const int tid = threadIdx.x;
    const int lane = tid & 63, w = tid >> 6;
    const int wm = w >> 1, wn = w & 1;
    const int l15 = lane & 15, quad = lane >> 4;
    const int M0 = blockIdx.y * 128, N0 = blockIdx.x * 128;
    const int bz = blockIdx.z;

    const u16* W = (bz == 0) ? Wq : (bz == 1) ? Wk : Wv;
    const float* bias = (bz == 0) ? bq : (bz == 1) ? bk : bv;
    const float* Wst = (bz == 0) ? Wqs : (bz == 1) ? Wks : Wvs;
    const float* bst = (bz == 0) ? bqs : (bz == 1) ? bks : bvs;

    f32x4 acc[4][4];
#pragma unroll
    for (int i = 0; i < 4; i++)
#pragma unroll
        for (int j = 0; j < 4; j++) acc[i][j] = (f32x4){0.f, 0.f, 0.f, 0.f};

    // staging: unit u in [0,512) of 16B; row=u>>2, lchunk=u&3, gchunk=lchunk^(row&3)
    int ua = w * 128 + lane;
    int r0 = ua >> 2, c0 = ((ua & 3) ^ (r0 & 3)) * 8;
    int ub = ua + 64;
    int r1 = ub >> 2, c1 = ((ub & 3) ^ (r1 & 3)) * 8;
    const u16* Ag0 = xb + (size_t)(M0 + r0) * 1024 + c0;
    const u16* Ag1 = xb + (size_t)(M0 + r1) * 1024 + c1;
    const u16* Wg0 = W + (size_t)(N0 + r0) * 1024 + c0;
    const u16* Wg1 = W + (size_t)(N0 + r1) * 1024 + c1;
    const u16* As0 = As + (w * 128) * 8;
    const u16* As1 = As + (w * 128 + 64) * 8;
    const u16* Bs0 = Bs + (w * 128) * 8;
    const u16* Bs1 = Bs + (w * 128 + 64) * 8;

    for (int k0 = 0; k0 < 1024; k0 += 32) {
        __syncthreads();
        async_cp16(Ag0 + k0, As0);
        async_cp16(Ag1 + k0, As1);
        async_cp16(Wg0 + k0, Bs0);
        async_cp16(Wg1 + k0, Bs1);
        __syncthreads();

        bf16x8 af[4], bf[4];
#pragma unroll
        for (int mi = 0; mi < 4; mi++)
            af[mi] = *(const bf16x8*)(As + (wm * 64 + mi * 16 + l15) * 32 + ((quad ^ (l15 & 3)) * 8));
#pragma unroll
        for (int ni = 0; ni < 4; ni++)
            bf[ni] = *(const bf16x8*)(Bs + (wn * 64 + ni * 16 + l15) * 32 + ((quad ^ (l15 & 3)) * 8));
#pragma unroll
        for (int mi = 0; mi < 4; mi++)
#pragma unroll
            for (int ni = 0; ni < 4; ni++)
                acc[mi][ni] = __builtin_amdgcn_mfma_f32_16x16x32_bf16(af[mi], bf[ni], acc[mi][ni], 0, 0, 0);
    }

    // ---- epilogue ----
    const float tau = temp_p[0] * 1.44269504088896f;
    const int nb = N0 + wn * 64;         // head base; h fixed per wave column
    const int h = nb >> 6;
    float bias_v[4], wst_v[3][4];
#pragma unroll
    for (int ni = 0; ni < 4; ni++) {
        bias_v[ni] = bias[nb + ni * 16 + l15];
#pragma unroll
        for (int c = 0; c < 3; c++) wst_v[c][ni] = Wst[c * 64 + ni * 16 + l15];
    }
    const float bst0 = bst[0], bst1 = bst[1], bst2 = bst[2];

#pragma unroll
    for (int mi = 0; mi < 4; mi++) {
        int m0 = M0 + wm * 64 + mi * 16 + quad * 4;
        int b = m0 >> 11, t0 = m0 & 2047;
        // per-row STP partials + quad reduction
        float p0[4], p1[4], p2[4];
#pragma unroll
        for (int r = 0; r < 4; r++) {
            float a0 = 0.f, a1 = 0.f, a2 = 0.f;
#pragma unroll
            for (int ni = 0; ni < 4; ni++) {
                float v = acc[mi][ni][r] + bias_v[ni];
                a0 += v * wst_v[0][ni];
                a1 += v * wst_v[1][ni];
                a2 += v * wst_v[2][ni];
            }
#pragma unroll
            for (int off = 1; off < 16; off <<= 1) {
                a0 += __shfl_xor(a0, off);
                a1 += __shfl_xor(a1, off);
                a2 += __shfl_xor(a2, off);
            }
            p0[r] = a0 + bst0; p1[r] = a1 + bst1; p2[r] = a2 + bst2;
        }

        if (bz == 0) {
            // qe rows: [0:64] = q*tau, [64:67] = qstp*tau, [67:96] = 0
#pragma unroll
            for (int r = 0; r < 4; r++) {
                size_t row = (size_t)((b * 16 + h) * 2048 + (t0 + r));
                u16* qer = qe + row * 96;
#pragma unroll
                for (int ni = 0; ni < 4; ni++)
                    qer[ni * 16 + l15] = f2b((acc[mi][ni][r] + bias_v[ni]) * tau);
                if (l15 == 0) {
                    *(u32*)(qer + 64) = pack2(p0[r] * tau, p1[r] * tau);
                    *(u32*)(qer + 66) = (u32)f2b(p2[r] * tau);
                    uint2 z = make_uint2(0u, 0u);
#pragma unroll
                    for (int j = 68; j < 96; j += 4) *(uint2*)(qer + j) = z;
                }
            }
        } else if (bz == 1) {
            // ke[0:64] raw + k3 side
#pragma unroll
            for (int r = 0; r < 4; r++) {
                size_t row = (size_t)((b * 16 + h) * 2048 + (t0 + r));
                u16* ker = ke + row * 96;
#pragma unroll
                for (int ni = 0; ni < 4; ni++)
                    ker[ni * 16 + l15] = f2b(acc[mi][ni][r] + bias_v[ni]);
                if (l15 == 0)
                    k3b[row] = make_float4(p0[r], p1[r], p2[r], 0.f);
            }
        } else {
            // vT [bh*64+hd][t] packed b64 + v3 side
#pragma unroll
            for (int ni = 0; ni < 4; ni++) {
                int hd = ni * 16 + l15;
                float v0 = acc[mi][ni][0] + bias_v[ni];
                float v1 = acc[mi][ni][1] + bias_v[ni];
                float v2 = acc[mi][ni][2] + bias_v[ni];
                float v3 = acc[mi][ni][3] + bias_v[ni];
                *(uint2*)(vT + ((size_t)((b * 16 + h) * 64 + hd)) * 2048 + t0) =
                    make_uint2(pack2(v0, v1), pack2(v2, v3));
            }
            if (l15 == 0) {
#pragma unroll
                for (int r = 0; r < 4; r++) {
                    size_t row = (size_t)((b * 16 + h) * 2048 + (t0 + r));
                    v3b[row] = make_float4(p0[r], p1[r], p2[r], 0.f);
                }
            }
        }
    }
}

// ---------------- finish: ke[64:67] = cross(k3,v3), ke[67:96] = 0 ----------------
__global__ void finish_ext_kernel(const float4* __restrict__ k3b, const float4* __restrict__ v3b,
                                  u16* __restrict__ ke)
{
    int row = blockIdx.x * blockDim.x + threadIdx.x;
    if (row >= 2 * 16 * 2048) return;
    float4 k3 = k3b[row];
    float4 v3 = v3b[row];
    float c0 = k3.y * v3.z - k3.z * v3.y;
    float c1 = k3.z * v3.x - k3.x * v3.z;
    float c2 = k3.x * v3.y - k3.y * v3.x;
    u16* ker = ke + (size_t)row * 96;
    *(u32*)(ker + 64) = pack2(c0, c1);
    *(u32*)(ker + 66) = (u32)f2b(c2);
    uint2 z = make_uint2(0u, 0u);
#pragma unroll
    for (int j = 68; j < 96; j += 4) *(uint2*)(ker + j) = z;
}

// ---------------- out-projection GEMM: 64x128 tiles for 2 blocks/CU ----------------
__global__ __launch_bounds__(256) void gemm_out_kernel(
    const u16* __restrict__ ao, const u16* __restrict__ Wo, const float* __restrict__ bo,
    float* __restrict__ out)
{
    __shared__ __align__(16) u16 As[64 * 32];
    __shared__ __align__(16) u16 Bs[128 * 32];
    const int tid = threadIdx.x;
    const int lane = tid & 63, w = tid >> 6;
    const int wm = w >> 1, wn = w & 1;
    const int l15 = lane & 15, quad = lane >> 4;
    const int M0 = blockIdx.y * 64, N0 = blockIdx.x * 128;

    f32x4 acc[2][4];
#pragma unroll
    for (int i = 0; i < 2; i++)
#pragma unroll
        for (int j = 0; j < 4; j++) acc[i][j] = (f32x4){0.f, 0.f, 0.f, 0.f};

    // A: 256 units (64 rows x 4 chunks), B: 512 units
    int ra = tid >> 2, ca = ((tid & 3) ^ (ra & 3)) * 8;
    int rb1 = ra + 64;  // (tid+256)>>2
    const u16* Aga = ao + (size_t)(M0 + ra) * 1024 + ca;
    const u16* Bg0 = Wo + (size_t)(N0 + ra) * 1024 + ca;
    const u16* Bg1 = Wo + (size_t)(N0 + rb1) * 1024 + ca;
    const u16* Asb = As + (w * 64) * 8;
    const u16* Bs0 = Bs + (w * 64) * 8;
    const u16* Bs1 = Bs + (256 + w * 64) * 8;

    for (int k0 = 0; k0 < 1024; k0 += 32) {
        __syncthreads();
        async_cp16(Aga + k0, Asb);
        async_cp16(Bg0 + k0, Bs0);
        async_cp16(Bg1 + k0, Bs1);
        __syncthreads();

        bf16x8 af[2], bf[4];
#pragma unroll
        for (int mi = 0; mi < 2; mi++)
            af[mi] = *(const bf16x8*)(As + (wm * 32 + mi * 16 + l15) * 32 + ((quad ^ (l15 & 3)) * 8));
#pragma unroll
        for (int ni = 0; ni < 4; ni++)
            bf[ni] = *(const bf16x8*)(Bs + (wn * 64 + ni * 16 + l15) * 32 + ((quad ^ (l15 & 3)) * 8));
#pragma unroll
        for (int mi = 0; mi < 2; mi++)
#pragma unroll
            for (int ni = 0; ni < 4; ni++)
                acc[mi][ni] = __builtin_amdgcn_mfma_f32_16x16x32_bf16(af[mi], bf[ni], acc[mi][ni], 0, 0, 0);
    }

#pragma unroll
    for (int mi = 0; mi < 2; mi++)
#pragma unroll
        for (int ni = 0; ni < 4; ni++) {
            int n = N0 + wn * 64 + ni * 16 + l15;
            float bias_n = bo[n];
            int m0 = M0 + wm * 32 + mi * 16 + quad * 4;
#pragma unroll
            for (int r = 0; r < 4; r++)
                out[(size_t)(m0 + r) * 1024 + n] = acc[mi][ni][r] + bias_n;
        }
}

// ---------------- flash attention (unchanged from round 6) ----------------
__global__ __launch_bounds__(256) void attn_kernel(
    const u16* __restrict__ qe, const u16* __restrict__ ke, const u16* __restrict__ vT,
    u16* __restrict__ out)
{
    __shared__ __align__(16) u16 Ks[64 * 128];
    __shared__ __align__(16) u16 Vt[64 * 64];
    __shared__ __align__(16) u16 Ps[128 * 64];

    const int tid = threadIdx.x;
    const int lane = tid & 63, w = tid >> 6;
    const int l15 = lane & 15, quad = lane >> 4;
    const int lsw = l15 & 7;
    const int bh = blockIdx.y;
    const int q0 = blockIdx.x * 128;

    const u16* qeb = qe + (size_t)bh * 2048 * 96;
    const u16* keb = ke + (size_t)bh * 2048 * 96;
    const u16* vTb = vT + (size_t)bh * 64 * 2048;

    bf16x8 bq[2][3];
#pragma unroll
    for (int s = 0; s < 2; s++) {
        const u16* qrow = qeb + (size_t)(q0 + w * 32 + s * 16 + l15) * 96;
#pragma unroll
        for (int ks = 0; ks < 3; ks++) bq[s][ks] = *(const bf16x8*)(qrow + ks * 32 + quad * 8);
    }

    f32x4 O[2][4];
    float l_part[2];
#pragma unroll
    for (int s = 0; s < 2; s++) {
        l_part[s] = 0.f;
#pragma unroll
        for (int dt = 0; dt < 4; dt++) O[s][dt] = (f32x4){0.f, 0.f, 0.f, 0.f};
    }

    const int srow = tid >> 2, spart = tid & 3;
    const int sh = srow & 7;
    u16* Pw[2];
#pragma unroll
    for (int s = 0; s < 2; s++) Pw[s] = Ps + (size_t)(w * 32 + s * 16 + l15) * 64;

    for (int kb = 0; kb < 2048; kb += 64) {
        const u16* kg = keb + (size_t)(kb + srow) * 96;
        uint4 kx0 = *(const uint4*)(kg + spart * 8);
        uint4 kx1 = *(const uint4*)(kg + (spart + 4) * 8);
        uint4 kx2 = *(const uint4*)(kg + (spart + 8) * 8);
        const u16* vg = vTb + (size_t)srow * 2048 + kb;
        uint4 vx0 = *(const uint4*)(vg + spart * 8);
        uint4 vx1 = *(const uint4*)(vg + (spart + 4) * 8);
        __syncthreads();
        *(uint4*)(Ks + srow * 128 + ((spart    ) ^ sh) * 8) = kx0;
        *(uint4*)(Ks + srow * 128 + ((spart + 4) ^ sh) * 8) = kx1;
        *(uint4*)(Ks + srow * 128 + ((spart + 8) ^ sh) * 8) = kx2;
        *(uint4*)(Vt + srow * 64 + ((spart    ) ^ sh) * 8) = vx0;
        *(uint4*)(Vt + srow * 64 + ((spart + 4) ^ sh) * 8) = vx1;
        __syncthreads();

        f32x4 S[2][4];
#pragma unroll
        for (int s = 0; s < 2; s++)
#pragma unroll
            for (int nt = 0; nt < 4; nt++) S[s][nt] = (f32x4){0.f, 0.f, 0.f, 0.f};
#pragma unroll
        for (int ks = 0; ks < 3; ks++) {
            bf16x8 ak[4];
#pragma unroll
            for (int nt = 0; nt < 4; nt++)
                ak[nt] = *(const bf16x8*)(Ks + (nt * 16 + l15) * 128 + (((ks * 4 + quad) ^ lsw) & 15) * 8);
#pragma unroll
            for (int s = 0; s < 2; s++)
#pragma unroll
                for (int nt = 0; nt < 4; nt++)
                    S[s][nt] = __builtin_amdgcn_mfma_f32_16x16x32_bf16(ak[nt], bq[s][ks], S[s][nt], 0, 0, 0);
        }

#pragma unroll
        for (int s = 0; s < 2; s++) {
            float sum = 0.f;
#pragma unroll
            for (int nt = 0; nt < 4; nt++)
#pragma unroll
                for (int r = 0; r < 4; r++) {
                    float p = __builtin_amdgcn_exp2f(S[s][nt][r]);
                    S[s][nt][r] = p;
                    sum += p;
                }
            l_part[s] += sum;
#pragma unroll
            for (int nt = 0; nt < 4; nt++) {
                int c = (nt * 2 + (quad >> 1)) ^ lsw;
                *(uint2*)(Pw[s] + c * 8 + (quad & 1) * 4) =
                    make_uint2(pack2(S[s][nt][0], S[s][nt][1]), pack2(S[s][nt][2], S[s][nt][3]));
            }
        }

#pragma unroll
        for (int kk = 0; kk < 2; kk++) {
            bf16x8 av[4];
#pragma unroll
            for (int dt = 0; dt < 4; dt++)
                av[dt] = *(const bf16x8*)(Vt + (dt * 16 + l15) * 64 + ((kk * 4 + quad) ^ lsw) * 8);
#pragma unroll
            for (int s = 0; s < 2; s++) {
                bf16x8 pb = *(const bf16x8*)(Pw[s] + ((kk * 4 + quad) ^ lsw) * 8);
#pragma unroll
                for (int dt = 0; dt < 4; dt++)
                    O[s][dt] = __builtin_amdgcn_mfma_f32_16x16x32_bf16(av[dt], pb, O[s][dt], 0, 0, 0);
            }
        }
    }

    const int b = bh >> 4, h = bh & 15;
#pragma unroll
    for (int s = 0; s < 2; s++) {
        float l = l_part[s];
        l += __shfl_xor(l, 16);
        l += __shfl_xor(l, 32);
        float linv = 1.0f / l;
        int tq = q0 + w * 32 + s * 16 + l15;
#pragma unroll
        for (int dt = 0; dt < 4; dt++) {
            int d = h * 64 + dt * 16 + quad * 4;
            *(uint2*)(out + (size_t)(b * 2048 + tq) * 1024 + d) =
                make_uint2(pack2(O[s][dt][0] * linv, O[s][dt][1] * linv),
                           pack2(O[s][dt][2] * linv, O[s][dt][3] * linv));
        }
    }
}

// ---------------- launch ----------------
extern "C" void kernel_launch(void* const* d_in, const int* in_sizes, int n_in,
                              void* d_out, int out_size, void* d_ws, size_t ws_size,
                              hipStream_t stream)
{
    (void)in_sizes; (void)n_in; (void)out_size; (void)ws_size;
    const float* x   = (const float*)d_in[0];
    const float* Wq  = (const float*)d_in[1];
    const float* bq  = (const float*)d_in[2];
    const float* Wk  = (const float*)d_in[3];
    const float* bk  = (const float*)d_in[4];
    const float* Wv  = (const float*)d_in[5];
    const float* bv  = (const float*)d_in[6];
    const float* Wo  = (const float*)d_in[7];
    const float* bo  = (const float*)d_in[8];
    const float* Wqs = (const float*)d_in[9];
    const float* bqs = (const float*)d_in[10];
    const float* Wks = (const float*)d_in[11];
    const float* bks = (const float*)d_in[12];
    const float* Wvs = (const float*)d_in[13];
    const float* bvs = (const float*)d_in[14];
    const float* temp = (const float*)d_in[15];

    char* ws = (char*)d_ws;
    u16* xb  = (u16*)(ws);                  // 8 MB (reused as aob after gemm_qkv... after attn writes)
    u16* Wqb = (u16*)(ws + 8388608);        // 2 MB
    u16* Wkb = (u16*)(ws + 10485760);       // 2 MB
    u16* Wvb = (u16*)(ws + 12582912);       // 2 MB
    u16* Wob = (u16*)(ws + 14680064);       // 2 MB
    u16* qeb = (u16*)(ws + 16777216);       // 12 MB [B,H,T,96]
    u16* keb = (u16*)(ws + 29360128);       // 12 MB
    u16* vTb = (u16*)(ws + 41943040);       // 8 MB  [B,H,64,T]
    float4* k3b = (float4*)(ws + 50331648); // 1 MB  [B*H*T]
    float4* v3b = (float4*)(ws + 51380224); // 1 MB
    u16* aob = (u16*)(ws + 52428800);       // 8 MB  [B,T,D]  (xb must stay live through gemm_qkv)

    cast_all_kernel<<<8192, 256, 0, stream>>>(x, Wq, Wk, Wv, Wo, xb, Wqb, Wkb, Wvb, Wob);
    gemm_qkv_kernel<<<dim3(8, 32, 3), 256, 0, stream>>>(
        xb, Wqb, Wkb, Wvb, bq, bk, bv, Wqs, bqs, Wks, bks, Wvs, bvs, temp,
        qeb, keb, vTb, k3b, v3b);
    finish_ext_kernel<<<256, 256, 0, stream>>>(k3b, v3b, keb);
    attn_kernel<<<dim3(16, 32), 256, 0, stream>>>(qeb, keb, vTb, aob);
    gemm_out_kernel<<<dim3(8, 64), 256, 0, stream>>>(aob, Wob, bo, (float*)d_out);
}

// Round 8
// 243.815 us; speedup vs baseline: 1.5990x; 1.0214x over previous
//
#include <hip/hip_runtime.h>
#include <stdint.h>

typedef unsigned short u16;
typedef unsigned int u32;
typedef __attribute__((ext_vector_type(8))) short bf16x8;
typedef __attribute__((ext_vector_type(4))) float f32x4;

__device__ __forceinline__ u16 f2b(float f) {
    union { float f; u32 u; } t; t.f = f;
    return (u16)((t.u + 0x7FFFu + ((t.u >> 16) & 1u)) >> 16);
}
__device__ __forceinline__ u32 pack2(float a, float b) {
    return (u32)f2b(a) | ((u32)f2b(b) << 16);
}

// async global->LDS 16B copy: per-lane global addr, wave-uniform LDS base + lane*16
__device__ __forceinline__ void async_cp16(const u16* g, const u16* lds_base) {
    __builtin_amdgcn_global_load_lds(
        (const __attribute__((address_space(1))) void*)(uintptr_t)g,
        (__attribute__((address_space(3))) void*)(u32)(uintptr_t)lds_base,
        16, 0, 0);
}

// ---------------- fused fp32 -> bf16 cast (x + 4 weights, one launch) ----------------
__global__ void cast_all_kernel(const float* __restrict__ x,
                                const float* __restrict__ Wq, const float* __restrict__ Wk,
                                const float* __restrict__ Wv, const float* __restrict__ Wo,
                                u16* __restrict__ xb, u16* __restrict__ Wqb, u16* __restrict__ Wkb,
                                u16* __restrict__ Wvb, u16* __restrict__ Wob) {
    int i = blockIdx.x * blockDim.x + threadIdx.x;  // float4 index, total 2097152
    const float* s; u16* d; int off;
    if (i < 1048576) { s = x; d = xb; off = i; }
    else {
        int j = i - 1048576;
        int w = j >> 18; off = j & 262143;
        if (w == 0) { s = Wq; d = Wqb; }
        else if (w == 1) { s = Wk; d = Wkb; }
        else if (w == 2) { s = Wv; d = Wvb; }
        else { s = Wo; d = Wob; }
    }
    float4 f = ((const float4*)s)[off];
    ((uint2*)d)[off] = make_uint2(pack2(f.x, f.y), pack2(f.z, f.w));
}

// ---------------- fused QKV GEMM + STP projections + qe/ke/vT emission ----------------
// 64x128 tiles (6 blocks/CU), global_load_lds staging, XOR chunk swizzle.
// z=0: qe rows [0:96] complete (temp*log2e folded), z=1: ke[0:64] + k3 side,
// z=2: vT [B,H,64,T] + v3 side.
__global__ __launch_bounds__(256) void gemm_qkv_kernel(
    const u16* __restrict__ xb,
    const u16* __restrict__ Wq, const u16* __restrict__ Wk, const u16* __restrict__ Wv,
    const float* __restrict__ bq, const float* __restrict__ bk, const float* __restrict__ bv,
    const float* __restrict__ Wqs, const float* __restrict__ bqs,
    const float* __restrict__ Wks, const float* __restrict__ bks,
    const float* __restrict__ Wvs, const float* __restrict__ bvs,
    const float* __restrict__ temp_p,
    u16* __restrict__ qe, u16* __restrict__ ke, u16* __restrict__ vT,
    float4* __restrict__ k3b, float4* __restrict__ v3b)
{
    __shared__ __align__(16) u16 As[64 * 32];
    __shared__ __align__(16) u16 Bs[128 * 32];
    const int tid = threadIdx.x;
    const int lane = tid & 63, w = tid >> 6;
    const int wm = w >> 1, wn = w & 1;
    const int l15 = lane & 15, quad = lane >> 4;
    const int M0 = blockIdx.y * 64, N0 = blockIdx.x * 128;
    const int bz = blockIdx.z;

    const u16* W = (bz == 0) ? Wq : (bz == 1) ? Wk : Wv;
    const float* bias = (bz == 0) ? bq : (bz == 1) ? bk : bv;
    const float* Wst = (bz == 0) ? Wqs : (bz == 1) ? Wks : Wvs;
    const float* bst = (bz == 0) ? bqs : (bz == 1) ? bks : bvs;

    f32x4 acc[2][4];
#pragma unroll
    for (int i = 0; i < 2; i++)
#pragma unroll
        for (int j = 0; j < 4; j++) acc[i][j] = (f32x4){0.f, 0.f, 0.f, 0.f};

    // staging: A 256 units (64 rows x 4 chunks), B 512 units; gchunk = lchunk^(row&3)
    int ra = tid >> 2, ca = ((tid & 3) ^ (ra & 3)) * 8;
    const u16* Aga = xb + (size_t)(M0 + ra) * 1024 + ca;
    const u16* Bg0 = W + (size_t)(N0 + ra) * 1024 + ca;
    const u16* Bg1 = W + (size_t)(N0 + ra + 64) * 1024 + ca;  // (ra+64)&3 == ra&3
    const u16* Asb = As + (w * 64) * 8;
    const u16* Bs0 = Bs + (w * 64) * 8;
    const u16* Bs1 = Bs + (256 + w * 64) * 8;

    for (int k0 = 0; k0 < 1024; k0 += 32) {
        __syncthreads();
        async_cp16(Aga + k0, Asb);
        async_cp16(Bg0 + k0, Bs0);
        async_cp16(Bg1 + k0, Bs1);
        __syncthreads();

        bf16x8 af[2], bf[4];
#pragma unroll
        for (int mi = 0; mi < 2; mi++)
            af[mi] = *(const bf16x8*)(As + (wm * 32 + mi * 16 + l15) * 32 + ((quad ^ (l15 & 3)) * 8));
#pragma unroll
        for (int ni = 0; ni < 4; ni++)
            bf[ni] = *(const bf16x8*)(Bs + (wn * 64 + ni * 16 + l15) * 32 + ((quad ^ (l15 & 3)) * 8));
#pragma unroll
        for (int mi = 0; mi < 2; mi++)
#pragma unroll
            for (int ni = 0; ni < 4; ni++)
                acc[mi][ni] = __builtin_amdgcn_mfma_f32_16x16x32_bf16(af[mi], bf[ni], acc[mi][ni], 0, 0, 0);
    }

    // ---- epilogue ----
    const float tau = temp_p[0] * 1.44269504088896f;
    const int nb = N0 + wn * 64;         // head base; h fixed per wave column
    const int h = nb >> 6;
    float bias_v[4], wst_v[3][4];
#pragma unroll
    for (int ni = 0; ni < 4; ni++) {
        bias_v[ni] = bias[nb + ni * 16 + l15];
#pragma unroll
        for (int c = 0; c < 3; c++) wst_v[c][ni] = Wst[c * 64 + ni * 16 + l15];
    }
    const float bst0 = bst[0], bst1 = bst[1], bst2 = bst[2];

#pragma unroll
    for (int mi = 0; mi < 2; mi++) {
        int m0 = M0 + wm * 32 + mi * 16 + quad * 4;
        int b = m0 >> 11, t0 = m0 & 2047;
        // per-row STP partials + quad reduction
        float p0[4], p1[4], p2[4];
#pragma unroll
        for (int r = 0; r < 4; r++) {
            float a0 = 0.f, a1 = 0.f, a2 = 0.f;
#pragma unroll
            for (int ni = 0; ni < 4; ni++) {
                float v = acc[mi][ni][r] + bias_v[ni];
                a0 += v * wst_v[0][ni];
                a1 += v * wst_v[1][ni];
                a2 += v * wst_v[2][ni];
            }
#pragma unroll
            for (int off = 1; off < 16; off <<= 1) {
                a0 += __shfl_xor(a0, off);
                a1 += __shfl_xor(a1, off);
                a2 += __shfl_xor(a2, off);
            }
            p0[r] = a0 + bst0; p1[r] = a1 + bst1; p2[r] = a2 + bst2;
        }

        if (bz == 0) {
            // qe rows: [0:64] = q*tau, [64:67] = qstp*tau, [67:96] = 0
#pragma unroll
            for (int r = 0; r < 4; r++) {
                size_t row = (size_t)((b * 16 + h) * 2048 + (t0 + r));
                u16* qer = qe + row * 96;
#pragma unroll
                for (int ni = 0; ni < 4; ni++)
                    qer[ni * 16 + l15] = f2b((acc[mi][ni][r] + bias_v[ni]) * tau);
                if (l15 == 0) {
                    *(u32*)(qer + 64) = pack2(p0[r] * tau, p1[r] * tau);
                    *(u32*)(qer + 66) = (u32)f2b(p2[r] * tau);
                    uint2 z = make_uint2(0u, 0u);
#pragma unroll
                    for (int j = 68; j < 96; j += 4) *(uint2*)(qer + j) = z;
                }
            }
        } else if (bz == 1) {
            // ke[0:64] raw + k3 side
#pragma unroll
            for (int r = 0; r < 4; r++) {
                size_t row = (size_t)((b * 16 + h) * 2048 + (t0 + r));
                u16* ker = ke + row * 96;
#pragma unroll
                for (int ni = 0; ni < 4; ni++)
                    ker[ni * 16 + l15] = f2b(acc[mi][ni][r] + bias_v[ni]);
                if (l15 == 0)
                    k3b[row] = make_float4(p0[r], p1[r], p2[r], 0.f);
            }
        } else {
            // vT [bh*64+hd][t] packed b64 + v3 side
#pragma unroll
            for (int ni = 0; ni < 4; ni++) {
                int hd = ni * 16 + l15;
                float v0 = acc[mi][ni][0] + bias_v[ni];
                float v1 = acc[mi][ni][1] + bias_v[ni];
                float v2 = acc[mi][ni][2] + bias_v[ni];
                float v3 = acc[mi][ni][3] + bias_v[ni];
                *(uint2*)(vT + ((size_t)((b * 16 + h) * 64 + hd)) * 2048 + t0) =
                    make_uint2(pack2(v0, v1), pack2(v2, v3));
            }
            if (l15 == 0) {
#pragma unroll
                for (int r = 0; r < 4; r++) {
                    size_t row = (size_t)((b * 16 + h) * 2048 + (t0 + r));
                    v3b[row] = make_float4(p0[r], p1[r], p2[r], 0.f);
                }
            }
        }
    }
}

// ---------------- finish: ke[64:67] = cross(k3,v3), ke[67:96] = 0 ----------------
__global__ void finish_ext_kernel(const float4* __restrict__ k3b, const float4* __restrict__ v3b,
                                  u16* __restrict__ ke)
{
    int row = blockIdx.x * blockDim.x + threadIdx.x;
    if (row >= 2 * 16 * 2048) return;
    float4 k3 = k3b[row];
    float4 v3 = v3b[row];
    float c0 = k3.y * v3.z - k3.z * v3.y;
    float c1 = k3.z * v3.x - k3.x * v3.z;
    float c2 = k3.x * v3.y - k3.y * v3.x;
    u16* ker = ke + (size_t)row * 96;
    *(u32*)(ker + 64) = pack2(c0, c1);
    *(u32*)(ker + 66) = (u32)f2b(c2);
    uint2 z = make_uint2(0u, 0u);
#pragma unroll
    for (int j = 68; j < 96; j += 4) *(uint2*)(ker + j) = z;
}

// ---------------- out-projection GEMM: 64x128 tiles ----------------
__global__ __launch_bounds__(256) void gemm_out_kernel(
    const u16* __restrict__ ao, const u16* __restrict__ Wo, const float* __restrict__ bo,
    float* __restrict__ out)
{
    __shared__ __align__(16) u16 As[64 * 32];
    __shared__ __align__(16) u16 Bs[128 * 32];
    const int tid = threadIdx.x;
    const int lane = tid & 63, w = tid >> 6;
    const int wm = w >> 1, wn = w & 1;
    const int l15 = lane & 15, quad = lane >> 4;
    const int M0 = blockIdx.y * 64, N0 = blockIdx.x * 128;

    f32x4 acc[2][4];
#pragma unroll
    for (int i = 0; i < 2; i++)
#pragma unroll
        for (int j = 0; j < 4; j++) acc[i][j] = (f32x4){0.f, 0.f, 0.f, 0.f};

    int ra = tid >> 2, ca = ((tid & 3) ^ (ra & 3)) * 8;
    const u16* Aga = ao + (size_t)(M0 + ra) * 1024 + ca;
    const u16* Bg0 = Wo + (size_t)(N0 + ra) * 1024 + ca;
    const u16* Bg1 = Wo + (size_t)(N0 + ra + 64) * 1024 + ca;
    const u16* Asb = As + (w * 64) * 8;
    const u16* Bs0 = Bs + (w * 64) * 8;
    const u16* Bs1 = Bs + (256 + w * 64) * 8;

    for (int k0 = 0; k0 < 1024; k0 += 32) {
        __syncthreads();
        async_cp16(Aga + k0, Asb);
        async_cp16(Bg0 + k0, Bs0);
        async_cp16(Bg1 + k0, Bs1);
        __syncthreads();

        bf16x8 af[2], bf[4];
#pragma unroll
        for (int mi = 0; mi < 2; mi++)
            af[mi] = *(const bf16x8*)(As + (wm * 32 + mi * 16 + l15) * 32 + ((quad ^ (l15 & 3)) * 8));
#pragma unroll
        for (int ni = 0; ni < 4; ni++)
            bf[ni] = *(const bf16x8*)(Bs + (wn * 64 + ni * 16 + l15) * 32 + ((quad ^ (l15 & 3)) * 8));
#pragma unroll
        for (int mi = 0; mi < 2; mi++)
#pragma unroll
            for (int ni = 0; ni < 4; ni++)
                acc[mi][ni] = __builtin_amdgcn_mfma_f32_16x16x32_bf16(af[mi], bf[ni], acc[mi][ni], 0, 0, 0);
    }

#pragma unroll
    for (int mi = 0; mi < 2; mi++)
#pragma unroll
        for (int ni = 0; ni < 4; ni++) {
            int n = N0 + wn * 64 + ni * 16 + l15;
            float bias_n = bo[n];
            int m0 = M0 + wm * 32 + mi * 16 + quad * 4;
#pragma unroll
            for (int r = 0; r < 4; r++)
                out[(size_t)(m0 + r) * 1024 + n] = acc[mi][ni][r] + bias_n;
        }
}

// ---------------- flash attention: + register-prefetch double buffer ----------------
__global__ __launch_bounds__(256) void attn_kernel(
    const u16* __restrict__ qe, const u16* __restrict__ ke, const u16* __restrict__ vT,
    u16* __restrict__ out)
{
    __shared__ __align__(16) u16 Ks[64 * 128];
    __shared__ __align__(16) u16 Vt[64 * 64];
    __shared__ __align__(16) u16 Ps[128 * 64];

    const int tid = threadIdx.x;
    const int lane = tid & 63, w = tid >> 6;
    const int l15 = lane & 15, quad = lane >> 4;
    const int lsw = l15 & 7;
    const int bh = blockIdx.y;
    const int q0 = blockIdx.x * 128;

    const u16* qeb = qe + (size_t)bh * 2048 * 96;
    const u16* keb = ke + (size_t)bh * 2048 * 96;
    const u16* vTb = vT + (size_t)bh * 64 * 2048;

    bf16x8 bq[2][3];
#pragma unroll
    for (int s = 0; s < 2; s++) {
        const u16* qrow = qeb + (size_t)(q0 + w * 32 + s * 16 + l15) * 96;
#pragma unroll
        for (int ks = 0; ks < 3; ks++) bq[s][ks] = *(const bf16x8*)(qrow + ks * 32 + quad * 8);
    }

    f32x4 O[2][4];
    float l_part[2];
#pragma unroll
    for (int s = 0; s < 2; s++) {
        l_part[s] = 0.f;
#pragma unroll
        for (int dt = 0; dt < 4; dt++) O[s][dt] = (f32x4){0.f, 0.f, 0.f, 0.f};
    }

    const int srow = tid >> 2, spart = tid & 3;
    const int sh = srow & 7;
    u16* Pw[2];
#pragma unroll
    for (int s = 0; s < 2; s++) Pw[s] = Ps + (size_t)(w * 32 + s * 16 + l15) * 64;

    // preload kb=0 into regs
    uint4 kx0, kx1, kx2, vx0, vx1;
    {
        const u16* kg = keb + (size_t)srow * 96;
        kx0 = *(const uint4*)(kg + spart * 8);
        kx1 = *(const uint4*)(kg + (spart + 4) * 8);
        kx2 = *(const uint4*)(kg + (spart + 8) * 8);
        const u16* vg = vTb + (size_t)srow * 2048;
        vx0 = *(const uint4*)(vg + spart * 8);
        vx1 = *(const uint4*)(vg + (spart + 4) * 8);
    }

    for (int kb = 0; kb < 2048; kb += 64) {
        __syncthreads();  // previous iter's LDS reads done
        *(uint4*)(Ks + srow * 128 + ((spart    ) ^ sh) * 8) = kx0;
        *(uint4*)(Ks + srow * 128 + ((spart + 4) ^ sh) * 8) = kx1;
        *(uint4*)(Ks + srow * 128 + ((spart + 8) ^ sh) * 8) = kx2;
        *(uint4*)(Vt + srow * 64 + ((spart    ) ^ sh) * 8) = vx0;
        *(uint4*)(Vt + srow * 64 + ((spart + 4) ^ sh) * 8) = vx1;
        __syncthreads();

        // prefetch next K-tile; latency overlaps this iter's compute
        if (kb + 64 < 2048) {
            const u16* kg = keb + (size_t)(kb + 64 + srow) * 96;
            kx0 = *(const uint4*)(kg + spart * 8);
            kx1 = *(const uint4*)(kg + (spart + 4) * 8);
            kx2 = *(const uint4*)(kg + (spart + 8) * 8);
            const u16* vg = vTb + (size_t)srow * 2048 + (kb + 64);
            vx0 = *(const uint4*)(vg + spart * 8);
            vx1 = *(const uint4*)(vg + (spart + 4) * 8);
        }

        f32x4 S[2][4];
#pragma unroll
        for (int s = 0; s < 2; s++)
#pragma unroll
            for (int nt = 0; nt < 4; nt++) S[s][nt] = (f32x4){0.f, 0.f, 0.f, 0.f};
#pragma unroll
        for (int ks = 0; ks < 3; ks++) {
            bf16x8 ak[4];
#pragma unroll
            for (int nt = 0; nt < 4; nt++)
                ak[nt] = *(const bf16x8*)(Ks + (nt * 16 + l15) * 128 + (((ks * 4 + quad) ^ lsw) & 15) * 8);
#pragma unroll
            for (int s = 0; s < 2; s++)
#pragma unroll
                for (int nt = 0; nt < 4; nt++)
                    S[s][nt] = __builtin_amdgcn_mfma_f32_16x16x32_bf16(ak[nt], bq[s][ks], S[s][nt], 0, 0, 0);
        }

#pragma unroll
        for (int s = 0; s < 2; s++) {
            float sum = 0.f;
#pragma unroll
            for (int nt = 0; nt < 4; nt++)
#pragma unroll
                for (int r = 0; r < 4; r++) {
                    float p = __builtin_amdgcn_exp2f(S[s][nt][r]);
                    S[s][nt][r] = p;
                    sum += p;
                }
            l_part[s] += sum;
#pragma unroll
            for (int nt = 0; nt < 4; nt++) {
                int c = (nt * 2 + (quad >> 1)) ^ lsw;
                *(uint2*)(Pw[s] + c * 8 + (quad & 1) * 4) =
                    make_uint2(pack2(S[s][nt][0], S[s][nt][1]), pack2(S[s][nt][2], S[s][nt][3]));
            }
        }

#pragma unroll
        for (int kk = 0; kk < 2; kk++) {
            bf16x8 av[4];
#pragma unroll
            for (int dt = 0; dt < 4; dt++)
                av[dt] = *(const bf16x8*)(Vt + (dt * 16 + l15) * 64 + ((kk * 4 + quad) ^ lsw) * 8);
#pragma unroll
            for (int s = 0; s < 2; s++) {
                bf16x8 pb = *(const bf16x8*)(Pw[s] + ((kk * 4 + quad) ^ lsw) * 8);
#pragma unroll
                for (int dt = 0; dt < 4; dt++)
                    O[s][dt] = __builtin_amdgcn_mfma_f32_16x16x32_bf16(av[dt], pb, O[s][dt], 0, 0, 0);
            }
        }
    }

    const int b = bh >> 4, h = bh & 15;
#pragma unroll
    for (int s = 0; s < 2; s++) {
        float l = l_part[s];
        l += __shfl_xor(l, 16);
        l += __shfl_xor(l, 32);
        float linv = 1.0f / l;
        int tq = q0 + w * 32 + s * 16 + l15;
#pragma unroll
        for (int dt = 0; dt < 4; dt++) {
            int d = h * 64 + dt * 16 + quad * 4;
            *(uint2*)(out + (size_t)(b * 2048 + tq) * 1024 + d) =
                make_uint2(pack2(O[s][dt][0] * linv, O[s][dt][1] * linv),
                           pack2(O[s][dt][2] * linv, O[s][dt][3] * linv));
        }
    }
}

// ---------------- launch ----------------
extern "C" void kernel_launch(void* const* d_in, const int* in_sizes, int n_in,
                              void* d_out, int out_size, void* d_ws, size_t ws_size,
                              hipStream_t stream)
{
    (void)in_sizes; (void)n_in; (void)out_size; (void)ws_size;
    const float* x   = (const float*)d_in[0];
    const float* Wq  = (const float*)d_in[1];
    const float* bq  = (const float*)d_in[2];
    const float* Wk  = (const float*)d_in[3];
    const float* bk  = (const float*)d_in[4];
    const float* Wv  = (const float*)d_in[5];
    const float* bv  = (const float*)d_in[6];
    const float* Wo  = (const float*)d_in[7];
    const float* bo  = (const float*)d_in[8];
    const float* Wqs = (const float*)d_in[9];
    const float* bqs = (const float*)d_in[10];
    const float* Wks = (const float*)d_in[11];
    const float* bks = (const float*)d_in[12];
    const float* Wvs = (const float*)d_in[13];
    const float* bvs = (const float*)d_in[14];
    const float* temp = (const float*)d_in[15];

    char* ws = (char*)d_ws;
    u16* xb  = (u16*)(ws);                  // 8 MB
    u16* Wqb = (u16*)(ws + 8388608);        // 2 MB
    u16* Wkb = (u16*)(ws + 10485760);       // 2 MB
    u16* Wvb = (u16*)(ws + 12582912);       // 2 MB
    u16* Wob = (u16*)(ws + 14680064);       // 2 MB
    u16* qeb = (u16*)(ws + 16777216);       // 12 MB [B,H,T,96]
    u16* keb = (u16*)(ws + 29360128);       // 12 MB
    u16* vTb = (u16*)(ws + 41943040);       // 8 MB  [B,H,64,T]
    float4* k3b = (float4*)(ws + 50331648); // 1 MB  [B*H*T]
    float4* v3b = (float4*)(ws + 51380224); // 1 MB
    u16* aob = (u16*)(ws + 52428800);       // 8 MB  [B,T,D]

    cast_all_kernel<<<8192, 256, 0, stream>>>(x, Wq, Wk, Wv, Wo, xb, Wqb, Wkb, Wvb, Wob);
    gemm_qkv_kernel<<<dim3(8, 64, 3), 256, 0, stream>>>(
        xb, Wqb, Wkb, Wvb, bq, bk, bv, Wqs, bqs, Wks, bks, Wvs, bvs, temp,
        qeb, keb, vTb, k3b, v3b);
    finish_ext_kernel<<<256, 256, 0, stream>>>(k3b, v3b, keb);
    attn_kernel<<<dim3(16, 32), 256, 0, stream>>>(qeb, keb, vTb, aob);
    gemm_out_kernel<<<dim3(8, 64), 256, 0, stream>>>(aob, Wob, bo, (float*)d_out);
}

// Round 9
// 233.897 us; speedup vs baseline: 1.6668x; 1.0424x over previous
//
#include <hip/hip_runtime.h>
#include <stdint.h>

typedef unsigned short u16;
typedef unsigned int u32;
typedef __attribute__((ext_vector_type(8))) short bf16x8;
typedef __attribute__((ext_vector_type(4))) float f32x4;

__device__ __forceinline__ u16 f2b(float f) {
    union { float f; u32 u; } t; t.f = f;
    return (u16)((t.u + 0x7FFFu + ((t.u >> 16) & 1u)) >> 16);
}
__device__ __forceinline__ u32 pack2(float a, float b) {
    return (u32)f2b(a) | ((u32)f2b(b) << 16);
}

// async global->LDS 16B copy: per-lane global addr, wave-uniform LDS base + lane*16
__device__ __forceinline__ void async_cp16(const u16* g, const u16* lds_base) {
    __builtin_amdgcn_global_load_lds(
        (const __attribute__((address_space(1))) void*)(uintptr_t)g,
        (__attribute__((address_space(3))) void*)(u32)(uintptr_t)lds_base,
        16, 0, 0);
}

// ---------------- fused fp32 -> bf16 cast (x + 4 weights, one launch) ----------------
__global__ void cast_all_kernel(const float* __restrict__ x,
                                const float* __restrict__ Wq, const float* __restrict__ Wk,
                                const float* __restrict__ Wv, const float* __restrict__ Wo,
                                u16* __restrict__ xb, u16* __restrict__ Wqb, u16* __restrict__ Wkb,
                                u16* __restrict__ Wvb, u16* __restrict__ Wob) {
    int i = blockIdx.x * blockDim.x + threadIdx.x;  // float4 index, total 2097152
    const float* s; u16* d; int off;
    if (i < 1048576) { s = x; d = xb; off = i; }
    else {
        int j = i - 1048576;
        int w = j >> 18; off = j & 262143;
        if (w == 0) { s = Wq; d = Wqb; }
        else if (w == 1) { s = Wk; d = Wkb; }
        else if (w == 2) { s = Wv; d = Wvb; }
        else { s = Wo; d = Wob; }
    }
    float4 f = ((const float4*)s)[off];
    ((uint2*)d)[off] = make_uint2(pack2(f.x, f.y), pack2(f.z, f.w));
}

// ---------------- fused QKV GEMM + STP projections + qe/ke/vT emission ----------------
// 64x128 tiles (6 blocks/CU), global_load_lds staging, XOR chunk swizzle.
__global__ __launch_bounds__(256) void gemm_qkv_kernel(
    const u16* __restrict__ xb,
    const u16* __restrict__ Wq, const u16* __restrict__ Wk, const u16* __restrict__ Wv,
    const float* __restrict__ bq, const float* __restrict__ bk, const float* __restrict__ bv,
    const float* __restrict__ Wqs, const float* __restrict__ bqs,
    const float* __restrict__ Wks, const float* __restrict__ bks,
    const float* __restrict__ Wvs, const float* __restrict__ bvs,
    const float* __restrict__ temp_p,
    u16* __restrict__ qe, u16* __restrict__ ke, u16* __restrict__ vT,
    float4* __restrict__ k3b, float4* __restrict__ v3b)
{
    __shared__ __align__(16) u16 As[64 * 32];
    __shared__ __align__(16) u16 Bs[128 * 32];
    const int tid = threadIdx.x;
    const int lane = tid & 63, w = tid >> 6;
    const int wm = w >> 1, wn = w & 1;
    const int l15 = lane & 15, quad = lane >> 4;
    const int M0 = blockIdx.y * 64, N0 = blockIdx.x * 128;
    const int bz = blockIdx.z;

    const u16* W = (bz == 0) ? Wq : (bz == 1) ? Wk : Wv;
    const float* bias = (bz == 0) ? bq : (bz == 1) ? bk : bv;
    const float* Wst = (bz == 0) ? Wqs : (bz == 1) ? Wks : Wvs;
    const float* bst = (bz == 0) ? bqs : (bz == 1) ? bks : bvs;

    f32x4 acc[2][4];
#pragma unroll
    for (int i = 0; i < 2; i++)
#pragma unroll
        for (int j = 0; j < 4; j++) acc[i][j] = (f32x4){0.f, 0.f, 0.f, 0.f};

    int ra = tid >> 2, ca = ((tid & 3) ^ (ra & 3)) * 8;
    const u16* Aga = xb + (size_t)(M0 + ra) * 1024 + ca;
    const u16* Bg0 = W + (size_t)(N0 + ra) * 1024 + ca;
    const u16* Bg1 = W + (size_t)(N0 + ra + 64) * 1024 + ca;
    const u16* Asb = As + (w * 64) * 8;
    const u16* Bs0 = Bs + (w * 64) * 8;
    const u16* Bs1 = Bs + (256 + w * 64) * 8;

    for (int k0 = 0; k0 < 1024; k0 += 32) {
        __syncthreads();
        async_cp16(Aga + k0, Asb);
        async_cp16(Bg0 + k0, Bs0);
        async_cp16(Bg1 + k0, Bs1);
        __syncthreads();

        bf16x8 af[2], bf[4];
#pragma unroll
        for (int mi = 0; mi < 2; mi++)
            af[mi] = *(const bf16x8*)(As + (wm * 32 + mi * 16 + l15) * 32 + ((quad ^ (l15 & 3)) * 8));
#pragma unroll
        for (int ni = 0; ni < 4; ni++)
            bf[ni] = *(const bf16x8*)(Bs + (wn * 64 + ni * 16 + l15) * 32 + ((quad ^ (l15 & 3)) * 8));
#pragma unroll
        for (int mi = 0; mi < 2; mi++)
#pragma unroll
            for (int ni = 0; ni < 4; ni++)
                acc[mi][ni] = __builtin_amdgcn_mfma_f32_16x16x32_bf16(af[mi], bf[ni], acc[mi][ni], 0, 0, 0);
    }

    // ---- epilogue ----
    const float tau = temp_p[0] * 1.44269504088896f;
    const int nb = N0 + wn * 64;
    const int h = nb >> 6;
    float bias_v[4], wst_v[3][4];
#pragma unroll
    for (int ni = 0; ni < 4; ni++) {
        bias_v[ni] = bias[nb + ni * 16 + l15];
#pragma unroll
        for (int c = 0; c < 3; c++) wst_v[c][ni] = Wst[c * 64 + ni * 16 + l15];
    }
    const float bst0 = bst[0], bst1 = bst[1], bst2 = bst[2];

#pragma unroll
    for (int mi = 0; mi < 2; mi++) {
        int m0 = M0 + wm * 32 + mi * 16 + quad * 4;
        int b = m0 >> 11, t0 = m0 & 2047;
        float p0[4], p1[4], p2[4];
#pragma unroll
        for (int r = 0; r < 4; r++) {
            float a0 = 0.f, a1 = 0.f, a2 = 0.f;
#pragma unroll
            for (int ni = 0; ni < 4; ni++) {
                float v = acc[mi][ni][r] + bias_v[ni];
                a0 += v * wst_v[0][ni];
                a1 += v * wst_v[1][ni];
                a2 += v * wst_v[2][ni];
            }
#pragma unroll
            for (int off = 1; off < 16; off <<= 1) {
                a0 += __shfl_xor(a0, off);
                a1 += __shfl_xor(a1, off);
                a2 += __shfl_xor(a2, off);
            }
            p0[r] = a0 + bst0; p1[r] = a1 + bst1; p2[r] = a2 + bst2;
        }

        if (bz == 0) {
#pragma unroll
            for (int r = 0; r < 4; r++) {
                size_t row = (size_t)((b * 16 + h) * 2048 + (t0 + r));
                u16* qer = qe + row * 96;
#pragma unroll
                for (int ni = 0; ni < 4; ni++)
                    qer[ni * 16 + l15] = f2b((acc[mi][ni][r] + bias_v[ni]) * tau);
                if (l15 == 0) {
                    *(u32*)(qer + 64) = pack2(p0[r] * tau, p1[r] * tau);
                    *(u32*)(qer + 66) = (u32)f2b(p2[r] * tau);
                    uint2 z = make_uint2(0u, 0u);
#pragma unroll
                    for (int j = 68; j < 96; j += 4) *(uint2*)(qer + j) = z;
                }
            }
        } else if (bz == 1) {
#pragma unroll
            for (int r = 0; r < 4; r++) {
                size_t row = (size_t)((b * 16 + h) * 2048 + (t0 + r));
                u16* ker = ke + row * 96;
#pragma unroll
                for (int ni = 0; ni < 4; ni++)
                    ker[ni * 16 + l15] = f2b(acc[mi][ni][r] + bias_v[ni]);
                if (l15 == 0)
                    k3b[row] = make_float4(p0[r], p1[r], p2[r], 0.f);
            }
        } else {
#pragma unroll
            for (int ni = 0; ni < 4; ni++) {
                int hd = ni * 16 + l15;
                float v0 = acc[mi][ni][0] + bias_v[ni];
                float v1 = acc[mi][ni][1] + bias_v[ni];
                float v2 = acc[mi][ni][2] + bias_v[ni];
                float v3 = acc[mi][ni][3] + bias_v[ni];
                *(uint2*)(vT + ((size_t)((b * 16 + h) * 64 + hd)) * 2048 + t0) =
                    make_uint2(pack2(v0, v1), pack2(v2, v3));
            }
            if (l15 == 0) {
#pragma unroll
                for (int r = 0; r < 4; r++) {
                    size_t row = (size_t)((b * 16 + h) * 2048 + (t0 + r));
                    v3b[row] = make_float4(p0[r], p1[r], p2[r], 0.f);
                }
            }
        }
    }
}

// ---------------- finish: ke[64:67] = cross(k3,v3), ke[67:96] = 0 ----------------
__global__ void finish_ext_kernel(const float4* __restrict__ k3b, const float4* __restrict__ v3b,
                                  u16* __restrict__ ke)
{
    int row = blockIdx.x * blockDim.x + threadIdx.x;
    if (row >= 2 * 16 * 2048) return;
    float4 k3 = k3b[row];
    float4 v3 = v3b[row];
    float c0 = k3.y * v3.z - k3.z * v3.y;
    float c1 = k3.z * v3.x - k3.x * v3.z;
    float c2 = k3.x * v3.y - k3.y * v3.x;
    u16* ker = ke + (size_t)row * 96;
    *(u32*)(ker + 64) = pack2(c0, c1);
    *(u32*)(ker + 66) = (u32)f2b(c2);
    uint2 z = make_uint2(0u, 0u);
#pragma unroll
    for (int j = 68; j < 96; j += 4) *(uint2*)(ker + j) = z;
}

// ---------------- out-projection GEMM: 64x128 tiles ----------------
__global__ __launch_bounds__(256) void gemm_out_kernel(
    const u16* __restrict__ ao, const u16* __restrict__ Wo, const float* __restrict__ bo,
    float* __restrict__ out)
{
    __shared__ __align__(16) u16 As[64 * 32];
    __shared__ __align__(16) u16 Bs[128 * 32];
    const int tid = threadIdx.x;
    const int lane = tid & 63, w = tid >> 6;
    const int wm = w >> 1, wn = w & 1;
    const int l15 = lane & 15, quad = lane >> 4;
    const int M0 = blockIdx.y * 64, N0 = blockIdx.x * 128;

    f32x4 acc[2][4];
#pragma unroll
    for (int i = 0; i < 2; i++)
#pragma unroll
        for (int j = 0; j < 4; j++) acc[i][j] = (f32x4){0.f, 0.f, 0.f, 0.f};

    int ra = tid >> 2, ca = ((tid & 3) ^ (ra & 3)) * 8;
    const u16* Aga = ao + (size_t)(M0 + ra) * 1024 + ca;
    const u16* Bg0 = Wo + (size_t)(N0 + ra) * 1024 + ca;
    const u16* Bg1 = Wo + (size_t)(N0 + ra + 64) * 1024 + ca;
    const u16* Asb = As + (w * 64) * 8;
    const u16* Bs0 = Bs + (w * 64) * 8;
    const u16* Bs1 = Bs + (256 + w * 64) * 8;

    for (int k0 = 0; k0 < 1024; k0 += 32) {
        __syncthreads();
        async_cp16(Aga + k0, Asb);
        async_cp16(Bg0 + k0, Bs0);
        async_cp16(Bg1 + k0, Bs1);
        __syncthreads();

        bf16x8 af[2], bf[4];
#pragma unroll
        for (int mi = 0; mi < 2; mi++)
            af[mi] = *(const bf16x8*)(As + (wm * 32 + mi * 16 + l15) * 32 + ((quad ^ (l15 & 3)) * 8));
#pragma unroll
        for (int ni = 0; ni < 4; ni++)
            bf[ni] = *(const bf16x8*)(Bs + (wn * 64 + ni * 16 + l15) * 32 + ((quad ^ (l15 & 3)) * 8));
#pragma unroll
        for (int mi = 0; mi < 2; mi++)
#pragma unroll
            for (int ni = 0; ni < 4; ni++)
                acc[mi][ni] = __builtin_amdgcn_mfma_f32_16x16x32_bf16(af[mi], bf[ni], acc[mi][ni], 0, 0, 0);
    }

#pragma unroll
    for (int mi = 0; mi < 2; mi++)
#pragma unroll
        for (int ni = 0; ni < 4; ni++) {
            int n = N0 + wn * 64 + ni * 16 + l15;
            float bias_n = bo[n];
            int m0 = M0 + wm * 32 + mi * 16 + quad * 4;
#pragma unroll
            for (int r = 0; r < 4; r++)
                out[(size_t)(m0 + r) * 1024 + n] = acc[mi][ni][r] + bias_n;
        }
}

// ---------------- flash attention: key-split waves (kw x qw), double-buffered
// Ks/Vt, ONE barrier/iter, max-free exp2 softmax, XOR-swizzled b128 LDS ----------------
// smem u16 offsets: Ks buf0=0, buf1=8192 (64x128 each); Vt buf0=16384, buf1=20480
// (64x64 each); Ps=24576 (128x64, wave-private columns). Reduction overlays dead bufs.
__global__ __launch_bounds__(256, 2) void attn_kernel(
    const u16* __restrict__ qe, const u16* __restrict__ ke, const u16* __restrict__ vT,
    u16* __restrict__ out)
{
    __shared__ __align__(16) u16 smem[32768];
    u16* const KsA = smem;
    u16* const VtA = smem + 16384;
    u16* const PsB = smem + 24576;

    const int tid = threadIdx.x;
    const int lane = tid & 63, w = tid >> 6;
    const int kw = w & 1, qw = w >> 1;   // key-half, q-half
    const int l15 = lane & 15, quad = lane >> 4;
    const int lsw = l15 & 7;
    const int bh = blockIdx.y;
    const int q0 = blockIdx.x * 128;

    const u16* qeb = qe + (size_t)bh * 2048 * 96;
    const u16* keb = ke + (size_t)bh * 2048 * 96;
    const u16* vTb = vT + (size_t)bh * 64 * 2048;

    // Q B-frags: 4 subtiles covering this wave's 64 q (q = q0 + qw*64 + s*16 + l15)
    bf16x8 bq[4][3];
#pragma unroll
    for (int s = 0; s < 4; s++) {
        const u16* qrow = qeb + (size_t)(q0 + qw * 64 + s * 16 + l15) * 96;
#pragma unroll
        for (int ks = 0; ks < 3; ks++) bq[s][ks] = *(const bf16x8*)(qrow + ks * 32 + quad * 8);
    }

    f32x4 O[4][4];          // partial over this wave's 32 keys: [q-subtile][d-tile]
    float l_part[4];
#pragma unroll
    for (int s = 0; s < 4; s++) {
        l_part[s] = 0.f;
#pragma unroll
        for (int dt = 0; dt < 4; dt++) O[s][dt] = (f32x4){0.f, 0.f, 0.f, 0.f};
    }

    const int srow = tid >> 2, spart = tid & 3;
    const int sh = srow & 7;
    u16* Pw[4];
#pragma unroll
    for (int s = 0; s < 4; s++) Pw[s] = PsB + (size_t)(qw * 64 + s * 16 + l15) * 64;

    // preheader: stage tile 0 into buffer 0
    {
        const u16* kg = keb + (size_t)srow * 96;
        uint4 a0 = *(const uint4*)(kg + spart * 8);
        uint4 a1 = *(const uint4*)(kg + (spart + 4) * 8);
        uint4 a2 = *(const uint4*)(kg + (spart + 8) * 8);
        const u16* vg = vTb + (size_t)srow * 2048;
        uint4 b0 = *(const uint4*)(vg + spart * 8);
        uint4 b1 = *(const uint4*)(vg + (spart + 4) * 8);
        *(uint4*)(KsA + srow * 128 + ((spart    ) ^ sh) * 8) = a0;
        *(uint4*)(KsA + srow * 128 + ((spart + 4) ^ sh) * 8) = a1;
        *(uint4*)(KsA + srow * 128 + ((spart + 8) ^ sh) * 8) = a2;
        *(uint4*)(VtA + srow * 64 + ((spart    ) ^ sh) * 8) = b0;
        *(uint4*)(VtA + srow * 64 + ((spart + 4) ^ sh) * 8) = b1;
    }
    __syncthreads();

    uint4 kx0, kx1, kx2, vx0, vx1;
    for (int kb = 0; kb < 2048; kb += 64) {
        const int buf = (kb >> 6) & 1;
        const u16* Ks = KsA + buf * 8192;
        const u16* Vt = VtA + buf * 4096;
        u16* Ksn = KsA + (buf ^ 1) * 8192;
        u16* Vtn = VtA + (buf ^ 1) * 4096;
        const bool more = (kb + 64) < 2048;

        if (more) {  // issue next tile's global loads; latency hides under compute
            const u16* kg = keb + (size_t)(kb + 64 + srow) * 96;
            kx0 = *(const uint4*)(kg + spart * 8);
            kx1 = *(const uint4*)(kg + (spart + 4) * 8);
            kx2 = *(const uint4*)(kg + (spart + 8) * 8);
            const u16* vg = vTb + (size_t)srow * 2048 + (kb + 64);
            vx0 = *(const uint4*)(vg + spart * 8);
            vx1 = *(const uint4*)(vg + (spart + 4) * 8);
        }

        // ---- St = K(own 32 keys) x Q^T(own 64 q): 8 tiles ----
        f32x4 S[4][2];
#pragma unroll
        for (int s = 0; s < 4; s++)
#pragma unroll
            for (int nt = 0; nt < 2; nt++) S[s][nt] = (f32x4){0.f, 0.f, 0.f, 0.f};
#pragma unroll
        for (int ks = 0; ks < 3; ks++) {
            bf16x8 ak[2];
#pragma unroll
            for (int nt = 0; nt < 2; nt++)
                ak[nt] = *(const bf16x8*)(Ks + (kw * 32 + nt * 16 + l15) * 128 + (((ks * 4 + quad) ^ lsw) & 15) * 8);
#pragma unroll
            for (int s = 0; s < 4; s++)
#pragma unroll
                for (int nt = 0; nt < 2; nt++)
                    S[s][nt] = __builtin_amdgcn_mfma_f32_16x16x32_bf16(ak[nt], bq[s][ks], S[s][nt], 0, 0, 0);
        }

        // ---- max-free exp2 softmax; P^T written to wave-private columns ----
#pragma unroll
        for (int s = 0; s < 4; s++) {
            float sum = 0.f;
#pragma unroll
            for (int nt = 0; nt < 2; nt++)
#pragma unroll
                for (int r = 0; r < 4; r++) {
                    float p = __builtin_amdgcn_exp2f(S[s][nt][r]);
                    S[s][nt][r] = p;
                    sum += p;
                }
            l_part[s] += sum;
#pragma unroll
            for (int nt = 0; nt < 2; nt++) {
                int c = (kw * 4 + nt * 2 + (quad >> 1)) ^ lsw;
                *(uint2*)(Pw[s] + c * 8 + (quad & 1) * 4) =
                    make_uint2(pack2(S[s][nt][0], S[s][nt][1]), pack2(S[s][nt][2], S[s][nt][3]));
            }
        }

        // ---- O(partial) += V^T(own keys) x P^T(own keys); in-wave DS ordering ----
        {
            bf16x8 av[4];
#pragma unroll
            for (int dt = 0; dt < 4; dt++)
                av[dt] = *(const bf16x8*)(Vt + (dt * 16 + l15) * 64 + (((kw * 4 + quad) ^ lsw) & 7) * 8);
#pragma unroll
            for (int s = 0; s < 4; s++) {
                bf16x8 pb = *(const bf16x8*)(Pw[s] + (((kw * 4 + quad) ^ lsw) & 7) * 8);
#pragma unroll
                for (int dt = 0; dt < 4; dt++)
                    O[s][dt] = __builtin_amdgcn_mfma_f32_16x16x32_bf16(av[dt], pb, O[s][dt], 0, 0, 0);
            }
        }

        if (more) {  // stage next tile into the other buffer
            *(uint4*)(Ksn + srow * 128 + ((spart    ) ^ sh) * 8) = kx0;
            *(uint4*)(Ksn + srow * 128 + ((spart + 4) ^ sh) * 8) = kx1;
            *(uint4*)(Ksn + srow * 128 + ((spart + 8) ^ sh) * 8) = kx2;
            *(uint4*)(Vtn + srow * 64 + ((spart    ) ^ sh) * 8) = vx0;
            *(uint4*)(Vtn + srow * 64 + ((spart + 4) ^ sh) * 8) = vx1;
        }
        __syncthreads();  // single barrier: covers buf-read-done AND nxt-write-done
    }

    // ---- cross-wave reduction: kw=1 partials -> LDS; kw=0 adds, divides, stores ----
    float* const Ored = (float*)smem;            // [q 128][stride 68 fp32] = 34816 B
    float* const Lr = (float*)(smem + 20480);    // 128 fp32 at byte 40960
    if (kw == 1) {
#pragma unroll
        for (int s = 0; s < 4; s++) {
            float l = l_part[s];
            l += __shfl_xor(l, 16);
            l += __shfl_xor(l, 32);
            if (lane < 16) Lr[qw * 64 + s * 16 + l15] = l;
            int qrow = qw * 64 + s * 16 + l15;
#pragma unroll
            for (int dt = 0; dt < 4; dt++) {
                int dc = dt ^ (l15 & 3);  // row-keyed chunk swizzle (symmetric R/W)
                *(float4*)(Ored + qrow * 68 + dc * 16 + quad * 4) =
                    make_float4(O[s][dt][0], O[s][dt][1], O[s][dt][2], O[s][dt][3]);
            }
        }
    }
    __syncthreads();
    if (kw == 0) {
        const int b = bh >> 4, h = bh & 15;
#pragma unroll
        for (int s = 0; s < 4; s++) {
            float l = l_part[s];
            l += __shfl_xor(l, 16);
            l += __shfl_xor(l, 32);
            int qrow = qw * 64 + s * 16 + l15;
            l += Lr[qrow];
            float linv = 1.0f / l;
            int tq = q0 + qrow;
#pragma unroll
            for (int dt = 0; dt < 4; dt++) {
                int dc = dt ^ (l15 & 3);
                float4 o2 = *(const float4*)(Ored + qrow * 68 + dc * 16 + quad * 4);
                int d = h * 64 + dt * 16 + quad * 4;
                *(uint2*)(out + (size_t)(b * 2048 + tq) * 1024 + d) =
                    make_uint2(pack2((O[s][dt][0] + o2.x) * linv, (O[s][dt][1] + o2.y) * linv),
                               pack2((O[s][dt][2] + o2.z) * linv, (O[s][dt][3] + o2.w) * linv));
            }
        }
    }
}

// ---------------- launch ----------------
extern "C" void kernel_launch(void* const* d_in, const int* in_sizes, int n_in,
                              void* d_out, int out_size, void* d_ws, size_t ws_size,
                              hipStream_t stream)
{
    (void)in_sizes; (void)n_in; (void)out_size; (void)ws_size;
    const float* x   = (const float*)d_in[0];
    const float* Wq  = (const float*)d_in[1];
    const float* bq  = (const float*)d_in[2];
    const float* Wk  = (const float*)d_in[3];
    const float* bk  = (const float*)d_in[4];
    const float* Wv  = (const float*)d_in[5];
    const float* bv  = (const float*)d_in[6];
    const float* Wo  = (const float*)d_in[7];
    const float* bo  = (const float*)d_in[8];
    const float* Wqs = (const float*)d_in[9];
    const float* bqs = (const float*)d_in[10];
    const float* Wks = (const float*)d_in[11];
    const float* bks = (const float*)d_in[12];
    const float* Wvs = (const float*)d_in[13];
    const float* bvs = (const float*)d_in[14];
    const float* temp = (const float*)d_in[15];

    char* ws = (char*)d_ws;
    u16* xb  = (u16*)(ws);                  // 8 MB
    u16* Wqb = (u16*)(ws + 8388608);        // 2 MB
    u16* Wkb = (u16*)(ws + 10485760);       // 2 MB
    u16* Wvb = (u16*)(ws + 12582912);       // 2 MB
    u16* Wob = (u16*)(ws + 14680064);       // 2 MB
    u16* qeb = (u16*)(ws + 16777216);       // 12 MB [B,H,T,96]
    u16* keb = (u16*)(ws + 29360128);       // 12 MB
    u16* vTb = (u16*)(ws + 41943040);       // 8 MB  [B,H,64,T]
    float4* k3b = (float4*)(ws + 50331648); // 1 MB  [B*H*T]
    float4* v3b = (float4*)(ws + 51380224); // 1 MB
    u16* aob = (u16*)(ws + 52428800);       // 8 MB  [B,T,D]

    cast_all_kernel<<<8192, 256, 0, stream>>>(x, Wq, Wk, Wv, Wo, xb, Wqb, Wkb, Wvb, Wob);
    gemm_qkv_kernel<<<dim3(8, 64, 3), 256, 0, stream>>>(
        xb, Wqb, Wkb, Wvb, bq, bk, bv, Wqs, bqs, Wks, bks, Wvs, bvs, temp,
        qeb, keb, vTb, k3b, v3b);
    finish_ext_kernel<<<256, 256, 0, stream>>>(k3b, v3b, keb);
    attn_kernel<<<dim3(16, 32), 256, 0, stream>>>(qeb, keb, vTb, aob);
    gemm_out_kernel<<<dim3(8, 64), 256, 0, stream>>>(aob, Wob, bo, (float*)d_out);
}

// Round 10
// 228.623 us; speedup vs baseline: 1.7052x; 1.0231x over previous
//
#include <hip/hip_runtime.h>
#include <stdint.h>

typedef unsigned short u16;
typedef unsigned int u32;
typedef __attribute__((ext_vector_type(8))) short bf16x8;
typedef __attribute__((ext_vector_type(4))) float f32x4;

__device__ __forceinline__ u16 f2b(float f) {
    union { float f; u32 u; } t; t.f = f;
    return (u16)((t.u + 0x7FFFu + ((t.u >> 16) & 1u)) >> 16);
}
__device__ __forceinline__ u32 pack2(float a, float b) {
    return (u32)f2b(a) | ((u32)f2b(b) << 16);
}

// async global->LDS 16B copy: per-lane global addr, wave-uniform LDS base + lane*16
__device__ __forceinline__ void async_cp16(const u16* g, const u16* lds_base) {
    __builtin_amdgcn_global_load_lds(
        (const __attribute__((address_space(1))) void*)(uintptr_t)g,
        (__attribute__((address_space(3))) void*)(u32)(uintptr_t)lds_base,
        16, 0, 0);
}

// ---------------- fused fp32 -> bf16 cast (x + 4 weights, one launch) ----------------
__global__ void cast_all_kernel(const float* __restrict__ x,
                                const float* __restrict__ Wq, const float* __restrict__ Wk,
                                const float* __restrict__ Wv, const float* __restrict__ Wo,
                                u16* __restrict__ xb, u16* __restrict__ Wqb, u16* __restrict__ Wkb,
                                u16* __restrict__ Wvb, u16* __restrict__ Wob) {
    int i = blockIdx.x * blockDim.x + threadIdx.x;  // float4 index, total 2097152
    const float* s; u16* d; int off;
    if (i < 1048576) { s = x; d = xb; off = i; }
    else {
        int j = i - 1048576;
        int w = j >> 18; off = j & 262143;
        if (w == 0) { s = Wq; d = Wqb; }
        else if (w == 1) { s = Wk; d = Wkb; }
        else if (w == 2) { s = Wv; d = Wvb; }
        else { s = Wo; d = Wob; }
    }
    float4 f = ((const float4*)s)[off];
    ((uint2*)d)[off] = make_uint2(pack2(f.x, f.y), pack2(f.z, f.w));
}

// ---------------- fused QKV GEMM + STP projections + qe/ke/vT emission ----------------
// 64x128 tiles (6 blocks/CU), DOUBLE-BUFFERED global_load_lds staging with one
// barrier/iter (tile i+1 loads fly under tile i compute), XOR chunk swizzle.
__global__ __launch_bounds__(256) void gemm_qkv_kernel(
    const u16* __restrict__ xb,
    const u16* __restrict__ Wq, const u16* __restrict__ Wk, const u16* __restrict__ Wv,
    const float* __restrict__ bq, const float* __restrict__ bk, const float* __restrict__ bv,
    const float* __restrict__ Wqs, const float* __restrict__ bqs,
    const float* __restrict__ Wks, const float* __restrict__ bks,
    const float* __restrict__ Wvs, const float* __restrict__ bvs,
    const float* __restrict__ temp_p,
    u16* __restrict__ qe, u16* __restrict__ ke, u16* __restrict__ vT,
    float4* __restrict__ k3b, float4* __restrict__ v3b)
{
    __shared__ __align__(16) u16 As[2 * 64 * 32];    // buf stride 2048 u16
    __shared__ __align__(16) u16 Bs[2 * 128 * 32];   // buf stride 4096 u16
    const int tid = threadIdx.x;
    const int lane = tid & 63, w = tid >> 6;
    const int wm = w >> 1, wn = w & 1;
    const int l15 = lane & 15, quad = lane >> 4;
    const int M0 = blockIdx.y * 64, N0 = blockIdx.x * 128;
    const int bz = blockIdx.z;

    const u16* W = (bz == 0) ? Wq : (bz == 1) ? Wk : Wv;
    const float* bias = (bz == 0) ? bq : (bz == 1) ? bk : bv;
    const float* Wst = (bz == 0) ? Wqs : (bz == 1) ? Wks : Wvs;
    const float* bst = (bz == 0) ? bqs : (bz == 1) ? bks : bvs;

    f32x4 acc[2][4];
#pragma unroll
    for (int i = 0; i < 2; i++)
#pragma unroll
        for (int j = 0; j < 4; j++) acc[i][j] = (f32x4){0.f, 0.f, 0.f, 0.f};

    int ra = tid >> 2, ca = ((tid & 3) ^ (ra & 3)) * 8;
    const u16* Aga = xb + (size_t)(M0 + ra) * 1024 + ca;
    const u16* Bg0 = W + (size_t)(N0 + ra) * 1024 + ca;
    const u16* Bg1 = W + (size_t)(N0 + ra + 64) * 1024 + ca;
    const int aoff = (w * 64) * 8;          // wave-uniform LDS unit offsets
    const int boff0 = (w * 64) * 8;
    const int boff1 = (256 + w * 64) * 8;

    // preheader: tile 0 -> buf 0
    async_cp16(Aga, As + aoff);
    async_cp16(Bg0, Bs + boff0);
    async_cp16(Bg1, Bs + boff1);
    __syncthreads();   // vmcnt drain: tile 0 resident

    for (int k0 = 0; k0 < 1024; k0 += 32) {
        const int buf = (k0 >> 5) & 1;
        const u16* Asr = As + buf * 2048;
        const u16* Bsr = Bs + buf * 4096;
        if (k0 + 32 < 1024) {   // issue next tile into idle buffer; flies under compute
            const int nb_ = buf ^ 1;
            async_cp16(Aga + k0 + 32, As + nb_ * 2048 + aoff);
            async_cp16(Bg0 + k0 + 32, Bs + nb_ * 4096 + boff0);
            async_cp16(Bg1 + k0 + 32, Bs + nb_ * 4096 + boff1);
        }

        bf16x8 af[2], bf[4];
#pragma unroll
        for (int mi = 0; mi < 2; mi++)
            af[mi] = *(const bf16x8*)(Asr + (wm * 32 + mi * 16 + l15) * 32 + ((quad ^ (l15 & 3)) * 8));
#pragma unroll
        for (int ni = 0; ni < 4; ni++)
            bf[ni] = *(const bf16x8*)(Bsr + (wn * 64 + ni * 16 + l15) * 32 + ((quad ^ (l15 & 3)) * 8));
#pragma unroll
        for (int mi = 0; mi < 2; mi++)
#pragma unroll
            for (int ni = 0; ni < 4; ni++)
                acc[mi][ni] = __builtin_amdgcn_mfma_f32_16x16x32_bf16(af[mi], bf[ni], acc[mi][ni], 0, 0, 0);

        __syncthreads();  // single barrier: buf read-done + next tile vmcnt drain
    }

    // ---- epilogue ----
    const float tau = temp_p[0] * 1.44269504088896f;
    const int nb = N0 + wn * 64;
    const int h = nb >> 6;
    float bias_v[4], wst_v[3][4];
#pragma unroll
    for (int ni = 0; ni < 4; ni++) {
        bias_v[ni] = bias[nb + ni * 16 + l15];
#pragma unroll
        for (int c = 0; c < 3; c++) wst_v[c][ni] = Wst[c * 64 + ni * 16 + l15];
    }
    const float bst0 = bst[0], bst1 = bst[1], bst2 = bst[2];

#pragma unroll
    for (int mi = 0; mi < 2; mi++) {
        int m0 = M0 + wm * 32 + mi * 16 + quad * 4;
        int b = m0 >> 11, t0 = m0 & 2047;
        float p0[4], p1[4], p2[4];
#pragma unroll
        for (int r = 0; r < 4; r++) {
            float a0 = 0.f, a1 = 0.f, a2 = 0.f;
#pragma unroll
            for (int ni = 0; ni < 4; ni++) {
                float v = acc[mi][ni][r] + bias_v[ni];
                a0 += v * wst_v[0][ni];
                a1 += v * wst_v[1][ni];
                a2 += v * wst_v[2][ni];
            }
#pragma unroll
            for (int off = 1; off < 16; off <<= 1) {
                a0 += __shfl_xor(a0, off);
                a1 += __shfl_xor(a1, off);
                a2 += __shfl_xor(a2, off);
            }
            p0[r] = a0 + bst0; p1[r] = a1 + bst1; p2[r] = a2 + bst2;
        }

        if (bz == 0) {
#pragma unroll
            for (int r = 0; r < 4; r++) {
                size_t row = (size_t)((b * 16 + h) * 2048 + (t0 + r));
                u16* qer = qe + row * 96;
#pragma unroll
                for (int ni = 0; ni < 4; ni++)
                    qer[ni * 16 + l15] = f2b((acc[mi][ni][r] + bias_v[ni]) * tau);
                if (l15 == 0) {
                    *(u32*)(qer + 64) = pack2(p0[r] * tau, p1[r] * tau);
                    *(u32*)(qer + 66) = (u32)f2b(p2[r] * tau);
                    uint2 z = make_uint2(0u, 0u);
#pragma unroll
                    for (int j = 68; j < 96; j += 4) *(uint2*)(qer + j) = z;
                }
            }
        } else if (bz == 1) {
#pragma unroll
            for (int r = 0; r < 4; r++) {
                size_t row = (size_t)((b * 16 + h) * 2048 + (t0 + r));
                u16* ker = ke + row * 96;
#pragma unroll
                for (int ni = 0; ni < 4; ni++)
                    ker[ni * 16 + l15] = f2b(acc[mi][ni][r] + bias_v[ni]);
                if (l15 == 0)
                    k3b[row] = make_float4(p0[r], p1[r], p2[r], 0.f);
            }
        } else {
#pragma unroll
            for (int ni = 0; ni < 4; ni++) {
                int hd = ni * 16 + l15;
                float v0 = acc[mi][ni][0] + bias_v[ni];
                float v1 = acc[mi][ni][1] + bias_v[ni];
                float v2 = acc[mi][ni][2] + bias_v[ni];
                float v3 = acc[mi][ni][3] + bias_v[ni];
                *(uint2*)(vT + ((size_t)((b * 16 + h) * 64 + hd)) * 2048 + t0) =
                    make_uint2(pack2(v0, v1), pack2(v2, v3));
            }
            if (l15 == 0) {
#pragma unroll
                for (int r = 0; r < 4; r++) {
                    size_t row = (size_t)((b * 16 + h) * 2048 + (t0 + r));
                    v3b[row] = make_float4(p0[r], p1[r], p2[r], 0.f);
                }
            }
        }
    }
}

// ---------------- finish: ke[64:67] = cross(k3,v3), ke[67:96] = 0 ----------------
__global__ void finish_ext_kernel(const float4* __restrict__ k3b, const float4* __restrict__ v3b,
                                  u16* __restrict__ ke)
{
    int row = blockIdx.x * blockDim.x + threadIdx.x;
    if (row >= 2 * 16 * 2048) return;
    float4 k3 = k3b[row];
    float4 v3 = v3b[row];
    float c0 = k3.y * v3.z - k3.z * v3.y;
    float c1 = k3.z * v3.x - k3.x * v3.z;
    float c2 = k3.x * v3.y - k3.y * v3.x;
    u16* ker = ke + (size_t)row * 96;
    *(u32*)(ker + 64) = pack2(c0, c1);
    *(u32*)(ker + 66) = (u32)f2b(c2);
    uint2 z = make_uint2(0u, 0u);
#pragma unroll
    for (int j = 68; j < 96; j += 4) *(uint2*)(ker + j) = z;
}

// ---------------- out-projection GEMM: 64x128 tiles, double-buffered async ----------------
__global__ __launch_bounds__(256) void gemm_out_kernel(
    const u16* __restrict__ ao, const u16* __restrict__ Wo, const float* __restrict__ bo,
    float* __restrict__ out)
{
    __shared__ __align__(16) u16 As[2 * 64 * 32];
    __shared__ __align__(16) u16 Bs[2 * 128 * 32];
    const int tid = threadIdx.x;
    const int lane = tid & 63, w = tid >> 6;
    const int wm = w >> 1, wn = w & 1;
    const int l15 = lane & 15, quad = lane >> 4;
    const int M0 = blockIdx.y * 64, N0 = blockIdx.x * 128;

    f32x4 acc[2][4];
#pragma unroll
    for (int i = 0; i < 2; i++)
#pragma unroll
        for (int j = 0; j < 4; j++) acc[i][j] = (f32x4){0.f, 0.f, 0.f, 0.f};

    int ra = tid >> 2, ca = ((tid & 3) ^ (ra & 3)) * 8;
    const u16* Aga = ao + (size_t)(M0 + ra) * 1024 + ca;
    const u16* Bg0 = Wo + (size_t)(N0 + ra) * 1024 + ca;
    const u16* Bg1 = Wo + (size_t)(N0 + ra + 64) * 1024 + ca;
    const int aoff = (w * 64) * 8;
    const int boff0 = (w * 64) * 8;
    const int boff1 = (256 + w * 64) * 8;

    async_cp16(Aga, As + aoff);
    async_cp16(Bg0, Bs + boff0);
    async_cp16(Bg1, Bs + boff1);
    __syncthreads();

    for (int k0 = 0; k0 < 1024; k0 += 32) {
        const int buf = (k0 >> 5) & 1;
        const u16* Asr = As + buf * 2048;
        const u16* Bsr = Bs + buf * 4096;
        if (k0 + 32 < 1024) {
            const int nb_ = buf ^ 1;
            async_cp16(Aga + k0 + 32, As + nb_ * 2048 + aoff);
            async_cp16(Bg0 + k0 + 32, Bs + nb_ * 4096 + boff0);
            async_cp16(Bg1 + k0 + 32, Bs + nb_ * 4096 + boff1);
        }

        bf16x8 af[2], bf[4];
#pragma unroll
        for (int mi = 0; mi < 2; mi++)
            af[mi] = *(const bf16x8*)(Asr + (wm * 32 + mi * 16 + l15) * 32 + ((quad ^ (l15 & 3)) * 8));
#pragma unroll
        for (int ni = 0; ni < 4; ni++)
            bf[ni] = *(const bf16x8*)(Bsr + (wn * 64 + ni * 16 + l15) * 32 + ((quad ^ (l15 & 3)) * 8));
#pragma unroll
        for (int mi = 0; mi < 2; mi++)
#pragma unroll
            for (int ni = 0; ni < 4; ni++)
                acc[mi][ni] = __builtin_amdgcn_mfma_f32_16x16x32_bf16(af[mi], bf[ni], acc[mi][ni], 0, 0, 0);

        __syncthreads();
    }

#pragma unroll
    for (int mi = 0; mi < 2; mi++)
#pragma unroll
        for (int ni = 0; ni < 4; ni++) {
            int n = N0 + wn * 64 + ni * 16 + l15;
            float bias_n = bo[n];
            int m0 = M0 + wm * 32 + mi * 16 + quad * 4;
#pragma unroll
            for (int r = 0; r < 4; r++)
                out[(size_t)(m0 + r) * 1024 + n] = acc[mi][ni][r] + bias_n;
        }
}

// ---------------- flash attention (unchanged from round 9) ----------------
__global__ __launch_bounds__(256, 2) void attn_kernel(
    const u16* __restrict__ qe, const u16* __restrict__ ke, const u16* __restrict__ vT,
    u16* __restrict__ out)
{
    __shared__ __align__(16) u16 smem[32768];
    u16* const KsA = smem;
    u16* const VtA = smem + 16384;
    u16* const PsB = smem + 24576;

    const int tid = threadIdx.x;
    const int lane = tid & 63, w = tid >> 6;
    const int kw = w & 1, qw = w >> 1;
    const int l15 = lane & 15, quad = lane >> 4;
    const int lsw = l15 & 7;
    const int bh = blockIdx.y;
    const int q0 = blockIdx.x * 128;

    const u16* qeb = qe + (size_t)bh * 2048 * 96;
    const u16* keb = ke + (size_t)bh * 2048 * 96;
    const u16* vTb = vT + (size_t)bh * 64 * 2048;

    bf16x8 bq[4][3];
#pragma unroll
    for (int s = 0; s < 4; s++) {
        const u16* qrow = qeb + (size_t)(q0 + qw * 64 + s * 16 + l15) * 96;
#pragma unroll
        for (int ks = 0; ks < 3; ks++) bq[s][ks] = *(const bf16x8*)(qrow + ks * 32 + quad * 8);
    }

    f32x4 O[4][4];
    float l_part[4];
#pragma unroll
    for (int s = 0; s < 4; s++) {
        l_part[s] = 0.f;
#pragma unroll
        for (int dt = 0; dt < 4; dt++) O[s][dt] = (f32x4){0.f, 0.f, 0.f, 0.f};
    }

    const int srow = tid >> 2, spart = tid & 3;
    const int sh = srow & 7;
    u16* Pw[4];
#pragma unroll
    for (int s = 0; s < 4; s++) Pw[s] = PsB + (size_t)(qw * 64 + s * 16 + l15) * 64;

    {
        const u16* kg = keb + (size_t)srow * 96;
        uint4 a0 = *(const uint4*)(kg + spart * 8);
        uint4 a1 = *(const uint4*)(kg + (spart + 4) * 8);
        uint4 a2 = *(const uint4*)(kg + (spart + 8) * 8);
        const u16* vg = vTb + (size_t)srow * 2048;
        uint4 b0 = *(const uint4*)(vg + spart * 8);
        uint4 b1 = *(const uint4*)(vg + (spart + 4) * 8);
        *(uint4*)(KsA + srow * 128 + ((spart    ) ^ sh) * 8) = a0;
        *(uint4*)(KsA + srow * 128 + ((spart + 4) ^ sh) * 8) = a1;
        *(uint4*)(KsA + srow * 128 + ((spart + 8) ^ sh) * 8) = a2;
        *(uint4*)(VtA + srow * 64 + ((spart    ) ^ sh) * 8) = b0;
        *(uint4*)(VtA + srow * 64 + ((spart + 4) ^ sh) * 8) = b1;
    }
    __syncthreads();

    uint4 kx0, kx1, kx2, vx0, vx1;
    for (int kb = 0; kb < 2048; kb += 64) {
        const int buf = (kb >> 6) & 1;
        const u16* Ks = KsA + buf * 8192;
        const u16* Vt = VtA + buf * 4096;
        u16* Ksn = KsA + (buf ^ 1) * 8192;
        u16* Vtn = VtA + (buf ^ 1) * 4096;
        const bool more = (kb + 64) < 2048;

        if (more) {
            const u16* kg = keb + (size_t)(kb + 64 + srow) * 96;
            kx0 = *(const uint4*)(kg + spart * 8);
            kx1 = *(const uint4*)(kg + (spart + 4) * 8);
            kx2 = *(const uint4*)(kg + (spart + 8) * 8);
            const u16* vg = vTb + (size_t)srow * 2048 + (kb + 64);
            vx0 = *(const uint4*)(vg + spart * 8);
            vx1 = *(const uint4*)(vg + (spart + 4) * 8);
        }

        f32x4 S[4][2];
#pragma unroll
        for (int s = 0; s < 4; s++)
#pragma unroll
            for (int nt = 0; nt < 2; nt++) S[s][nt] = (f32x4){0.f, 0.f, 0.f, 0.f};
#pragma unroll
        for (int ks = 0; ks < 3; ks++) {
            bf16x8 ak[2];
#pragma unroll
            for (int nt = 0; nt < 2; nt++)
                ak[nt] = *(const bf16x8*)(Ks + (kw * 32 + nt * 16 + l15) * 128 + (((ks * 4 + quad) ^ lsw) & 15) * 8);
#pragma unroll
            for (int s = 0; s < 4; s++)
#pragma unroll
                for (int nt = 0; nt < 2; nt++)
                    S[s][nt] = __builtin_amdgcn_mfma_f32_16x16x32_bf16(ak[nt], bq[s][ks], S[s][nt], 0, 0, 0);
        }

#pragma unroll
        for (int s = 0; s < 4; s++) {
            float sum = 0.f;
#pragma unroll
            for (int nt = 0; nt < 2; nt++)
#pragma unroll
                for (int r = 0; r < 4; r++) {
                    float p = __builtin_amdgcn_exp2f(S[s][nt][r]);
                    S[s][nt][r] = p;
                    sum += p;
                }
            l_part[s] += sum;
#pragma unroll
            for (int nt = 0; nt < 2; nt++) {
                int c = (kw * 4 + nt * 2 + (quad >> 1)) ^ lsw;
                *(uint2*)(Pw[s] + c * 8 + (quad & 1) * 4) =
                    make_uint2(pack2(S[s][nt][0], S[s][nt][1]), pack2(S[s][nt][2], S[s][nt][3]));
            }
        }

        {
            bf16x8 av[4];
#pragma unroll
            for (int dt = 0; dt < 4; dt++)
                av[dt] = *(const bf16x8*)(Vt + (dt * 16 + l15) * 64 + (((kw * 4 + quad) ^ lsw) & 7) * 8);
#pragma unroll
            for (int s = 0; s < 4; s++) {
                bf16x8 pb = *(const bf16x8*)(Pw[s] + (((kw * 4 + quad) ^ lsw) & 7) * 8);
#pragma unroll
                for (int dt = 0; dt < 4; dt++)
                    O[s][dt] = __builtin_amdgcn_mfma_f32_16x16x32_bf16(av[dt], pb, O[s][dt], 0, 0, 0);
            }
        }

        if (more) {
            *(uint4*)(Ksn + srow * 128 + ((spart    ) ^ sh) * 8) = kx0;
            *(uint4*)(Ksn + srow * 128 + ((spart + 4) ^ sh) * 8) = kx1;
            *(uint4*)(Ksn + srow * 128 + ((spart + 8) ^ sh) * 8) = kx2;
            *(uint4*)(Vtn + srow * 64 + ((spart    ) ^ sh) * 8) = vx0;
            *(uint4*)(Vtn + srow * 64 + ((spart + 4) ^ sh) * 8) = vx1;
        }
        __syncthreads();
    }

    float* const Ored = (float*)smem;
    float* const Lr = (float*)(smem + 20480);
    if (kw == 1) {
#pragma unroll
        for (int s = 0; s < 4; s++) {
            float l = l_part[s];
            l += __shfl_xor(l, 16);
            l += __shfl_xor(l, 32);
            if (lane < 16) Lr[qw * 64 + s * 16 + l15] = l;
            int qrow = qw * 64 + s * 16 + l15;
#pragma unroll
            for (int dt = 0; dt < 4; dt++) {
                int dc = dt ^ (l15 & 3);
                *(float4*)(Ored + qrow * 68 + dc * 16 + quad * 4) =
                    make_float4(O[s][dt][0], O[s][dt][1], O[s][dt][2], O[s][dt][3]);
            }
        }
    }
    __syncthreads();
    if (kw == 0) {
        const int b = bh >> 4, h = bh & 15;
#pragma unroll
        for (int s = 0; s < 4; s++) {
            float l = l_part[s];
            l += __shfl_xor(l, 16);
            l += __shfl_xor(l, 32);
            int qrow = qw * 64 + s * 16 + l15;
            l += Lr[qrow];
            float linv = 1.0f / l;
            int tq = q0 + qrow;
#pragma unroll
            for (int dt = 0; dt < 4; dt++) {
                int dc = dt ^ (l15 & 3);
                float4 o2 = *(const float4*)(Ored + qrow * 68 + dc * 16 + quad * 4);
                int d = h * 64 + dt * 16 + quad * 4;
                *(uint2*)(out + (size_t)(b * 2048 + tq) * 1024 + d) =
                    make_uint2(pack2((O[s][dt][0] + o2.x) * linv, (O[s][dt][1] + o2.y) * linv),
                               pack2((O[s][dt][2] + o2.z) * linv, (O[s][dt][3] + o2.w) * linv));
            }
        }
    }
}

// ---------------- launch ----------------
extern "C" void kernel_launch(void* const* d_in, const int* in_sizes, int n_in,
                              void* d_out, int out_size, void* d_ws, size_t ws_size,
                              hipStream_t stream)
{
    (void)in_sizes; (void)n_in; (void)out_size; (void)ws_size;
    const float* x   = (const float*)d_in[0];
    const float* Wq  = (const float*)d_in[1];
    const float* bq  = (const float*)d_in[2];
    const float* Wk  = (const float*)d_in[3];
    const float* bk  = (const float*)d_in[4];
    const float* Wv  = (const float*)d_in[5];
    const float* bv  = (const float*)d_in[6];
    const float* Wo  = (const float*)d_in[7];
    const float* bo  = (const float*)d_in[8];
    const float* Wqs = (const float*)d_in[9];
    const float* bqs = (const float*)d_in[10];
    const float* Wks = (const float*)d_in[11];
    const float* bks = (const float*)d_in[12];
    const float* Wvs = (const float*)d_in[13];
    const float* bvs = (const float*)d_in[14];
    const float* temp = (const float*)d_in[15];

    char* ws = (char*)d_ws;
    u16* xb  = (u16*)(ws);                  // 8 MB
    u16* Wqb = (u16*)(ws + 8388608);        // 2 MB
    u16* Wkb = (u16*)(ws + 10485760);       // 2 MB
    u16* Wvb = (u16*)(ws + 12582912);       // 2 MB
    u16* Wob = (u16*)(ws + 14680064);       // 2 MB
    u16* qeb = (u16*)(ws + 16777216);       // 12 MB [B,H,T,96]
    u16* keb = (u16*)(ws + 29360128);       // 12 MB
    u16* vTb = (u16*)(ws + 41943040);       // 8 MB  [B,H,64,T]
    float4* k3b = (float4*)(ws + 50331648); // 1 MB  [B*H*T]
    float4* v3b = (float4*)(ws + 51380224); // 1 MB
    u16* aob = (u16*)(ws + 52428800);       // 8 MB  [B,T,D]

    cast_all_kernel<<<8192, 256, 0, stream>>>(x, Wq, Wk, Wv, Wo, xb, Wqb, Wkb, Wvb, Wob);
    gemm_qkv_kernel<<<dim3(8, 64, 3), 256, 0, stream>>>(
        xb, Wqb, Wkb, Wvb, bq, bk, bv, Wqs, bqs, Wks, bks, Wvs, bvs, temp,
        qeb, keb, vTb, k3b, v3b);
    finish_ext_kernel<<<256, 256, 0, stream>>>(k3b, v3b, keb);
    attn_kernel<<<dim3(16, 32), 256, 0, stream>>>(qeb, keb, vTb, aob);
    gemm_out_kernel<<<dim3(8, 64), 256, 0, stream>>>(aob, Wob, bo, (float*)d_out);
}